// Round 6
// baseline (2675.234 us; speedup 1.0000x reference)
//
#include <hip/hip_runtime.h>

#define N_NODES 10000
#define N_EDGES 320000
#define HD      256

typedef __attribute__((ext_vector_type(8))) short bf16x8;
typedef __attribute__((ext_vector_type(4))) float f32x4;
#define MFMA16 __builtin_amdgcn_mfma_f32_16x16x32_bf16

// ---------------------------------------------------------------------------
// ws layout (floats), max offset 12,941,584 fl = 51.77 MB (proven r3/r5)
//   P_s  @ 0           [N,256]
//   P_d  @ 2,560,000   [N,256]
//   bufA @ 5,120,000   t1 -> P1s
//   bufB @ 7,680,000   x1 -> (dead) -> WAf/WBf/WcF + pWA/pWB/pWc
//   bufC @ 10,240,000  agg -> P1d
//   deg  @ 12,800,000  [N]
//   bc   @ 12,810,000  [256]   (be1b+be0b)@Wp1 + bp1
//   bA   @ 12,810,256  [256]   be0b@WeE + be1a
//   pW0  @ 12,810,512  We0b split H|L (131,072 ushorts)
// ---------------------------------------------------------------------------
#define OFF_PD   2560000
#define OFF_BA   5120000
#define OFF_BB   7680000
#define OFF_BC   10240000
#define OFF_DEG  12800000
#define OFF_BCV  12810000
#define OFF_BAV  12810256
#define OFF_PW0  12810512

__device__ __forceinline__ ushort f2bf(float x) {
  union { float f; unsigned u; } c; c.f = x;
  unsigned r = (c.u + 0x7FFFu + ((c.u >> 16) & 1u)) >> 16;
  return (ushort)r;
}
__device__ __forceinline__ float bf2f(ushort h) {
  union { float f; unsigned u; } c; c.u = ((unsigned)h) << 16; return c.f;
}

// ---------------------------------------------------------------------------
// prep_split: W[256][256] fp32 -> fragment-linear split-bf16 H|L (validated r3)
// slot=(s*16+cfg)*64+lane holds j=0..7: W[s*32+(lane>>4)*8+j][cfg*16+(lane&15)]
// ---------------------------------------------------------------------------
__global__ __launch_bounds__(256)
void prep_split(const float* __restrict__ W, ushort* __restrict__ H,
                ushort* __restrict__ L)
{
  int slot = blockIdx.x * 256 + threadIdx.x;
  int s    = slot >> 10;
  int rem  = slot & 1023;
  int cf   = rem >> 6;
  int lane = rem & 63;
  int k0 = s * 32 + ((lane >> 4) << 3);
  int n  = cf * 16 + (lane & 15);
#pragma unroll
  for (int j = 0; j < 8; ++j) {
    float v = W[(k0 + j) * HD + n];
    ushort hi = f2bf(v);
    H[slot * 8 + j] = hi;
    L[slot * 8 + j] = f2bf(v - bf2f(hi));
  }
}

// ---------------------------------------------------------------------------
// node GEMM (fp32 VALU, unchanged — validated)
// ---------------------------------------------------------------------------
__global__ __launch_bounds__(256)
void node_gemm(const float* __restrict__ A1, int K1,
               const float* __restrict__ A2, int K2,
               const float* __restrict__ scale,
               const float* __restrict__ W,
               const float* __restrict__ bias,
               float* __restrict__ C, int M, int act)
{
  __shared__ float sA[64 * 36];
  __shared__ float sB[32 * 256];
  __shared__ float sBias[256];
  const int tid = threadIdx.x;
  const int r0  = blockIdx.x * 64;
  if (bias) sBias[tid] = bias[tid];
  const int ty = tid >> 4, tx = tid & 15;

  float acc[4][16];
#pragma unroll
  for (int r = 0; r < 4; r++)
#pragma unroll
    for (int c = 0; c < 16; c++) acc[r][c] = 0.f;

  const int K = K1 + K2;
  const int arow = tid >> 2;
  const int aks  = (tid & 3) * 8;
  const int gr_a = r0 + arow;

  for (int kb = 0; kb < K; kb += 32) {
    const float* Ap; int lda, koff; float sc = 1.0f;
    if (kb < K1) { Ap = A1; lda = K1; koff = kb; }
    else { Ap = A2; lda = K2; koff = kb - K1;
           if (scale) sc = scale[gr_a < M ? gr_a : M - 1]; }
#pragma unroll
    for (int j = 0; j < 8; j += 4) {
      float4 v;
      if (gr_a < M) v = *(const float4*)&Ap[(long)gr_a * lda + koff + aks + j];
      else { v.x = v.y = v.z = v.w = 0.f; }
      v.x *= sc; v.y *= sc; v.z *= sc; v.w *= sc;
      *(float4*)&sA[arow * 36 + aks + j] = v;
    }
#pragma unroll
    for (int j = 0; j < 8; j++) {
      int i = tid + 256 * j, row = i >> 6, c4 = i & 63;
      *(float4*)&sB[row * HD + c4 * 4] = *(const float4*)&W[(long)(kb + row) * HD + c4 * 4];
    }
    __syncthreads();
#pragma unroll 4
    for (int kk = 0; kk < 32; kk++) {
      float a0 = sA[(ty * 4 + 0) * 36 + kk];
      float a1 = sA[(ty * 4 + 1) * 36 + kk];
      float a2 = sA[(ty * 4 + 2) * 36 + kk];
      float a3 = sA[(ty * 4 + 3) * 36 + kk];
#pragma unroll
      for (int c = 0; c < 16; c++) {
        float b = sB[kk * HD + tx + 16 * c];
        acc[0][c] += a0 * b; acc[1][c] += a1 * b;
        acc[2][c] += a2 * b; acc[3][c] += a3 * b;
      }
    }
    __syncthreads();
  }

#pragma unroll
  for (int r = 0; r < 4; r++) {
    int gr = r0 + ty * 4 + r;
    if (gr >= M) continue;
#pragma unroll
    for (int c = 0; c < 16; c++) {
      int col = tx + 16 * c;
      float v = acc[r][c];
      if (bias) v += sBias[col];
      if (act)  v = fmaxf(v, 0.f);
      C[(long)gr * HD + col] = v;
    }
  }
}

// out[j] = base[j] + sum_k (v1[k] + v2?[k]) * W[k][j]
__global__ __launch_bounds__(256)
void bias_fold_k(const float* __restrict__ v1, const float* __restrict__ v2,
                 const float* __restrict__ W, const float* __restrict__ base,
                 float* __restrict__ out)
{
  const int j = threadIdx.x;
  float s = base[j];
  for (int k = 0; k < HD; k++) {
    float v = v1[k] + (v2 ? v2[k] : 0.f);
    s += v * W[k * HD + j];
  }
  out[j] = s;
}

__global__ void rdeg_k(float* __restrict__ deg)
{
  int i = blockIdx.x * blockDim.x + threadIdx.x;
  if (i < N_NODES) deg[i] = 1.0f / fmaxf(deg[i], 1.0f);
}

// ---------------------------------------------------------------------------
// build_h0 (512 threads, 32 edges): h0 = relu(Ps[s]+Pd[d]+ea@W6+b0) -> Ah/Al
// 16 threads/edge (el=tid>>4, q=tid&15), 16 cols each.
// A tile LDS: bf16 [32][256] hi+lo, row stride 512B, byte^=(row&7)<<4.
// W6/b0/eattr read straight from global (uniform-ish -> L1 broadcast).
// ---------------------------------------------------------------------------
__device__ __forceinline__ void build_h0(
    int tid, const float* __restrict__ Ps, const float* __restrict__ Pd,
    const float* __restrict__ eattr, long e0,
    const float* __restrict__ W6, const float* __restrict__ b0,
    const int* sSrc, const int* sDst, ushort* Ah, ushort* Al)
{
  const int el = tid >> 4, q = tid & 15;
  const int sv = sSrc[el], dv = sDst[el];
  const long e = e0 + el;
  float eav[6];
#pragma unroll
  for (int k = 0; k < 6; ++k) eav[k] = eattr[e * 6 + k];
  const float* ps = Ps + (long)sv * HD + q * 16;
  const float* pd = Pd + (long)dv * HD + q * 16;
  const int sw = (el & 7) << 4;
  char* ahB = (char*)Ah + el * 512;
  char* alB = (char*)Al + el * 512;
#pragma unroll
  for (int jj = 0; jj < 4; ++jj) {
    float4 a  = *(const float4*)(ps + jj * 4);
    float4 b  = *(const float4*)(pd + jj * 4);
    float4 bb = *(const float4*)(b0 + q * 16 + jj * 4);
    float vx = a.x + b.x + bb.x;
    float vy = a.y + b.y + bb.y;
    float vz = a.z + b.z + bb.z;
    float vw = a.w + b.w + bb.w;
#pragma unroll
    for (int k = 0; k < 6; ++k) {
      float4 w = *(const float4*)(W6 + k * HD + q * 16 + jj * 4);
      vx += eav[k] * w.x; vy += eav[k] * w.y;
      vz += eav[k] * w.z; vw += eav[k] * w.w;
    }
    vx = fmaxf(vx, 0.f); vy = fmaxf(vy, 0.f);
    vz = fmaxf(vz, 0.f); vw = fmaxf(vw, 0.f);
    ushort4 hh, ll;
    hh.x = f2bf(vx); hh.y = f2bf(vy); hh.z = f2bf(vz); hh.w = f2bf(vw);
    ll.x = f2bf(vx - bf2f(hh.x)); ll.y = f2bf(vy - bf2f(hh.y));
    ll.z = f2bf(vz - bf2f(hh.z)); ll.w = f2bf(vw - bf2f(hh.w));
    const int off = (q * 32 + jj * 8) ^ sw;
    *(ushort4*)(ahB + off) = hh;
    *(ushort4*)(alB + off) = ll;
  }
}

__device__ __forceinline__ void write_split(ushort* Ah, ushort* Al,
                                            int row, int col, float v)
{
  const int off = row * 512 + ((col * 2) ^ ((row & 7) << 4));
  ushort hi = f2bf(v);
  *(ushort*)((char*)Ah + off) = hi;
  *(ushort*)((char*)Al + off) = f2bf(v - bf2f(hi));
}

__device__ __forceinline__ void load_afrag(const ushort* Ah, const ushort* Al,
    int row, int s, int lane, bf16x8& ah, bf16x8& al)
{
  const int aoff = row * 512 + ((((s << 6) + ((lane >> 4) << 4))) ^ ((row & 7) << 4));
  ah = *(const bf16x8*)((const char*)Ah + aoff);
  al = *(const bf16x8*)((const char*)Al + aoff);
}

// single-B bf16x3 GEMM pass: acc[cf] += A(32x256) @ W(256x256) col-slice(wc)
__device__ __forceinline__ void gemm_pass(
    const ushort* __restrict__ pW,
    const ushort* Ah, const ushort* Al,
    int lane, int wc, int arow, f32x4 acc[4])
{
  const bf16x8* pH = (const bf16x8*)pW;
  const bf16x8* pL = (const bf16x8*)(pW + 65536);
#pragma unroll 2
  for (int s = 0; s < 8; ++s) {
    bf16x8 ah, al;
    load_afrag(Ah, Al, arow, s, lane, ah, al);
#pragma unroll
    for (int cf = 0; cf < 4; ++cf) {
      const int slot = s * 1024 + (wc * 4 + cf) * 64 + lane;
      bf16x8 bh = pH[slot];
      bf16x8 bl = pL[slot];
      acc[cf] = MFMA16(al, bh, acc[cf], 0, 0, 0);
      acc[cf] = MFMA16(ah, bl, acc[cf], 0, 0, 0);
      acc[cf] = MFMA16(ah, bh, acc[cf], 0, 0, 0);
    }
  }
}

// ---------------------------------------------------------------------------
// conv_in edge stage: h0 -> ea1 = h0@We0b + be0b -> atomic agg/deg.
// 512 threads, 32 edges/block, ~33KB LDS -> 4 blocks/CU, 8 waves/SIMD.
// ---------------------------------------------------------------------------
__global__ __launch_bounds__(512, 8)
void edge_conv_in(const int* __restrict__ ei, const float* __restrict__ eattr,
                  const float* __restrict__ Ps, const float* __restrict__ Pd,
                  const float* __restrict__ W6, const float* __restrict__ b0,
                  const ushort* __restrict__ pW0,
                  const float* __restrict__ be0b,
                  float* __restrict__ agg, float* __restrict__ deg)
{
  __shared__ ushort Ah[32 * 256];
  __shared__ ushort Al[32 * 256];
  __shared__ int    sSrc[32], sDst[32];
  const int tid = threadIdx.x;
  const long e0 = (long)blockIdx.x * 32;

  if (tid < 32) {
    int dv = ei[N_EDGES + e0 + tid];
    sDst[tid] = dv;
    atomicAdd(&deg[dv], 1.0f);
  } else if (tid < 64) {
    sSrc[tid - 32] = ei[e0 + tid - 32];
  }
  __syncthreads();

  build_h0(tid, Ps, Pd, eattr, e0, W6, b0, sSrc, sDst, Ah, Al);
  __syncthreads();

  const int lane = tid & 63, wid = tid >> 6;
  const int wc = wid & 3, wrg = wid >> 2;        // 4 col groups x 2 row groups
  const int arow = wrg * 16 + (lane & 15);

  f32x4 acc[4];
#pragma unroll
  for (int cf = 0; cf < 4; ++cf) acc[cf] = (f32x4){0.f, 0.f, 0.f, 0.f};
  gemm_pass(pW0, Ah, Al, lane, wc, arow, acc);

  const int rbase = wrg * 16 + ((lane >> 4) << 2);
#pragma unroll
  for (int cf = 0; cf < 4; ++cf) {
    const int col = wc * 64 + cf * 16 + (lane & 15);
    const float bv = be0b[col];
#pragma unroll
    for (int r = 0; r < 4; ++r)
      atomicAdd(&agg[(long)sDst[rbase + r] * HD + col], acc[cf][r] + bv);
  }
}

// ---------------------------------------------------------------------------
// Fused conv[0] edge MLP + predictor (ea1 algebraically folded out):
//   h0  = relu(Ps[s]+Pd[d]+ea@W6+b0)
//   h1  = relu(h0@WA + P1s[s]+P1d[d]+bA)     WA = We0b@WeE, bA = be0b@WeE+be1a
//   t   = h0@WB                              WB = We0b@Wp1  (reg-resident)
//   z   = h1@Wc + t + bc                     Wc = We1b@Wp1, bc=(be1b+be0b)@Wp1+bp1
//   out = leaky_relu(z)@Wp2 + bp2
// 512 threads, 32 edges/block, 3 sequential single-B GEMM passes.
// ---------------------------------------------------------------------------
__global__ __launch_bounds__(512, 8)
void edge_pred(const int* __restrict__ ei, const float* __restrict__ eattr,
               const float* __restrict__ Ps, const float* __restrict__ Pd,
               const float* __restrict__ W6, const float* __restrict__ b0,
               const float* __restrict__ P1s, const float* __restrict__ P1d,
               const ushort* __restrict__ pWA, const ushort* __restrict__ pWB,
               const ushort* __restrict__ pWc,
               const float* __restrict__ bA, const float* __restrict__ bc,
               const float* __restrict__ Wp2, const float* __restrict__ bp2,
               float* __restrict__ out)
{
  __shared__ ushort Ah[32 * 256];
  __shared__ ushort Al[32 * 256];
  __shared__ float  sOut[32];
  __shared__ int    sSrc[32], sDst[32];
  const int tid = threadIdx.x;
  const long e0 = (long)blockIdx.x * 32;

  if (tid < 32) {
    sDst[tid] = ei[N_EDGES + e0 + tid];
    sOut[tid] = bp2[0];
  } else if (tid < 64) {
    sSrc[tid - 32] = ei[e0 + tid - 32];
  }
  __syncthreads();

  build_h0(tid, Ps, Pd, eattr, e0, W6, b0, sSrc, sDst, Ah, Al);
  __syncthreads();

  const int lane = tid & 63, wid = tid >> 6;
  const int wc = wid & 3, wrg = wid >> 2;
  const int arow = wrg * 16 + (lane & 15);
  const int rbase = wrg * 16 + ((lane >> 4) << 2);

  // ---- pass 1: acc1 = h0@WA ----
  f32x4 acc1[4];
#pragma unroll
  for (int cf = 0; cf < 4; ++cf) acc1[cf] = (f32x4){0.f, 0.f, 0.f, 0.f};
  gemm_pass(pWA, Ah, Al, lane, wc, arow, acc1);

  // ---- pass 2: accT = h0@WB ----
  f32x4 accT[4];
#pragma unroll
  for (int cf = 0; cf < 4; ++cf) accT[cf] = (f32x4){0.f, 0.f, 0.f, 0.f};
  gemm_pass(pWB, Ah, Al, lane, wc, arow, accT);
  __syncthreads();   // all h0 reads complete before overwriting the A tile

  // ---- epilogue: h1 = relu(acc1 + P1s[s]+P1d[d]+bA) -> A tile ----
#pragma unroll
  for (int cf = 0; cf < 4; ++cf) {
    const int col = wc * 64 + cf * 16 + (lane & 15);
    const float bv = bA[col];
#pragma unroll
    for (int r = 0; r < 4; ++r) {
      const int row = rbase + r;
      float v = acc1[cf][r] + P1s[(long)sSrc[row] * HD + col]
                            + P1d[(long)sDst[row] * HD + col] + bv;
      write_split(Ah, Al, row, col, fmaxf(v, 0.f));
    }
  }
  __syncthreads();

  // ---- pass 3: accZ = h1@Wc ----
  f32x4 accZ[4];
#pragma unroll
  for (int cf = 0; cf < 4; ++cf) accZ[cf] = (f32x4){0.f, 0.f, 0.f, 0.f};
  gemm_pass(pWc, Ah, Al, lane, wc, arow, accZ);

  // ---- finale: z = accZ + accT + bc; leaky; dot Wp2; reduce ----
  float p[4] = {0.f, 0.f, 0.f, 0.f};
#pragma unroll
  for (int cf = 0; cf < 4; ++cf) {
    const int col = wc * 64 + cf * 16 + (lane & 15);
    const float w   = Wp2[col];
    const float bcv = bc[col];
#pragma unroll
    for (int r = 0; r < 4; ++r) {
      float z = accZ[cf][r] + accT[cf][r] + bcv;
      z = z > 0.f ? z : 0.01f * z;
      p[r] += z * w;
    }
  }
#pragma unroll
  for (int r = 0; r < 4; ++r) {
    p[r] += __shfl_xor(p[r], 1);
    p[r] += __shfl_xor(p[r], 2);
    p[r] += __shfl_xor(p[r], 4);
    p[r] += __shfl_xor(p[r], 8);
  }
  if ((lane & 15) == 0) {
#pragma unroll
    for (int r = 0; r < 4; ++r) atomicAdd(&sOut[rbase + r], p[r]);
  }
  __syncthreads();
  if (tid < 32) out[e0 + tid] = sOut[tid];
}

// ---------------------------------------------------------------------------
extern "C" void kernel_launch(void* const* d_in, const int* in_sizes, int n_in,
                              void* d_out, int out_size, void* d_ws, size_t ws_size,
                              hipStream_t stream)
{
  const float* x     = (const float*)d_in[0];
  const int*   ei    = (const int*)d_in[1];
  const float* eattr = (const float*)d_in[2];
  const float* We0a  = (const float*)d_in[3];
  const float* be0a  = (const float*)d_in[4];
  const float* We0b  = (const float*)d_in[5];
  const float* be0b  = (const float*)d_in[6];
  const float* Wn0a  = (const float*)d_in[7];
  const float* bn0a  = (const float*)d_in[8];
  const float* Wn0b  = (const float*)d_in[9];
  const float* bn0b  = (const float*)d_in[10];
  const float* We1a  = (const float*)d_in[11];
  const float* be1a  = (const float*)d_in[12];
  const float* We1b  = (const float*)d_in[13];
  const float* be1b  = (const float*)d_in[14];
  // d_in[15..18] dead (conv[0] node MLP never reaches the output)
  const float* Wp1   = (const float*)d_in[19];
  const float* bp1   = (const float*)d_in[20];
  const float* Wp2   = (const float*)d_in[21];
  const float* bp2   = (const float*)d_in[22];
  float* out = (float*)d_out;
  float* ws  = (float*)d_ws;

  float* P_s  = ws;
  float* P_d  = ws + OFF_PD;
  float* bufA = ws + OFF_BA;
  float* bufB = ws + OFF_BB;
  float* bufC = ws + OFF_BC;
  float* deg  = ws + OFF_DEG;
  float* bcB  = ws + OFF_BCV;
  float* bAB  = ws + OFF_BAV;
  ushort* pW0 = (ushort*)(ws + OFF_PW0);

  // composite-weight area inside bufB (dead after P1s/P1d are produced)
  float*  WAf = ws + OFF_BB;
  float*  WBf = ws + OFF_BB + 65536;
  float*  WcF = ws + OFF_BB + 131072;
  ushort* pWA = (ushort*)(ws + OFF_BB + 196608);
  ushort* pWB = (ushort*)(ws + OFF_BB + 262144);
  ushort* pWc = (ushort*)(ws + OFF_BB + 327680);

  const float* W6  = We0a + 1024 * HD;   // edge_attr rows of We0a
  const float* WeE = We1a + 512 * HD;    // ea1 rows of We1a

  // zero agg + deg (contiguous)
  hipMemsetAsync(bufC, 0, (2560000 + 10000) * sizeof(float), stream);

  const int ngrid = (N_NODES + 63) / 64;   // 157
  const int egrid = N_EDGES / 32;          // 10000

  // node projections + conv_in prep
  node_gemm<<<ngrid, 256, 0, stream>>>(x, 512, nullptr, 0, nullptr, We0a,            nullptr, P_s, N_NODES, 0);
  node_gemm<<<ngrid, 256, 0, stream>>>(x, 512, nullptr, 0, nullptr, We0a + 512 * HD, nullptr, P_d, N_NODES, 0);
  prep_split<<<32, 256, 0, stream>>>(We0b, pW0, pW0 + 65536);
  bias_fold_k<<<1, 256, 0, stream>>>(be1b, be0b, Wp1, bp1, bcB);     // bc'
  bias_fold_k<<<1, 256, 0, stream>>>(be0b, nullptr, WeE, be1a, bAB); // bA

  // conv_in edge stage -> agg, deg
  edge_conv_in<<<egrid, 512, 0, stream>>>(ei, eattr, P_s, P_d, W6, be0a,
                                          pW0, be0b, bufC, deg);
  rdeg_k<<<(N_NODES + 255) / 256, 256, 0, stream>>>(deg);

  // node pipeline
  node_gemm<<<ngrid, 256, 0, stream>>>(x, 512, bufC, 256, deg, Wn0a, bn0a, bufA, N_NODES, 1);          // t1
  node_gemm<<<ngrid, 256, 0, stream>>>(bufA, 256, nullptr, 0, nullptr, Wn0b, bn0b, bufB, N_NODES, 0);  // x1
  node_gemm<<<ngrid, 256, 0, stream>>>(bufB, 256, nullptr, 0, nullptr, We1a,            nullptr, bufA, N_NODES, 0); // P1s
  node_gemm<<<ngrid, 256, 0, stream>>>(bufB, 256, nullptr, 0, nullptr, We1a + 256 * HD, nullptr, bufC, N_NODES, 0); // P1d

  // composite weights (bufB/x1 now dead): WA=We0b@WeE, WB=We0b@Wp1, Wc=We1b@Wp1
  node_gemm<<<4, 256, 0, stream>>>(We0b, 256, nullptr, 0, nullptr, WeE, nullptr, WAf, 256, 0);
  node_gemm<<<4, 256, 0, stream>>>(We0b, 256, nullptr, 0, nullptr, Wp1, nullptr, WBf, 256, 0);
  node_gemm<<<4, 256, 0, stream>>>(We1b, 256, nullptr, 0, nullptr, Wp1, nullptr, WcF, 256, 0);
  prep_split<<<32, 256, 0, stream>>>(WAf, pWA, pWA + 65536);
  prep_split<<<32, 256, 0, stream>>>(WBf, pWB, pWB + 65536);
  prep_split<<<32, 256, 0, stream>>>(WcF, pWc, pWc + 65536);

  // fused conv[0] edge MLP + predictor
  edge_pred<<<egrid, 512, 0, stream>>>(ei, eattr, P_s, P_d, W6, be0a,
      bufA, bufC, pWA, pWB, pWc, bAB, bcB, Wp2, bp2, out);
}

// Round 7
// 2452.794 us; speedup vs baseline: 1.0907x; 1.0907x over previous
//
#include <hip/hip_runtime.h>

#define N_NODES 10000
#define N_EDGES 320000
#define HD      256

typedef __attribute__((ext_vector_type(8))) short bf16x8;
typedef __attribute__((ext_vector_type(4))) float f32x4;
#define MFMA16 __builtin_amdgcn_mfma_f32_16x16x32_bf16

// ---------------------------------------------------------------------------
// ws layout (floats), max offset 12,941,584 fl = 51.77 MB (proven r3/r5)
//   P_s  @ 0           [N,256]
//   P_d  @ 2,560,000   [N,256]
//   bufA @ 5,120,000   t1 -> P1s
//   bufB @ 7,680,000   x1 -> (dead) -> WAf/WBf/WcF + pWA/pWB/pWc
//   bufC @ 10,240,000  agg -> P1d
//   deg  @ 12,800,000  [N]
//   bc   @ 12,810,000  [256]   (be1b+be0b)@Wp1 + bp1
//   bA   @ 12,810,256  [256]   be0b@WeE + be1a
//   pW0  @ 12,810,512  We0b split H|L (131,072 ushorts)
// ---------------------------------------------------------------------------
#define OFF_PD   2560000
#define OFF_BA   5120000
#define OFF_BB   7680000
#define OFF_BC   10240000
#define OFF_DEG  12800000
#define OFF_BCV  12810000
#define OFF_BAV  12810256
#define OFF_PW0  12810512

__device__ __forceinline__ ushort f2bf(float x) {
  union { float f; unsigned u; } c; c.f = x;
  unsigned r = (c.u + 0x7FFFu + ((c.u >> 16) & 1u)) >> 16;
  return (ushort)r;
}
__device__ __forceinline__ float bf2f(ushort h) {
  union { float f; unsigned u; } c; c.u = ((unsigned)h) << 16; return c.f;
}

// ---------------------------------------------------------------------------
// prep_split: W[256][256] fp32 -> fragment-linear split-bf16 H|L (validated r3)
// slot=(s*16+cfg)*64+lane holds j=0..7: W[s*32+(lane>>4)*8+j][cfg*16+(lane&15)]
// ---------------------------------------------------------------------------
__global__ __launch_bounds__(256)
void prep_split(const float* __restrict__ W, ushort* __restrict__ H,
                ushort* __restrict__ L)
{
  int slot = blockIdx.x * 256 + threadIdx.x;
  int s    = slot >> 10;
  int rem  = slot & 1023;
  int cf   = rem >> 6;
  int lane = rem & 63;
  int k0 = s * 32 + ((lane >> 4) << 3);
  int n  = cf * 16 + (lane & 15);
#pragma unroll
  for (int j = 0; j < 8; ++j) {
    float v = W[(k0 + j) * HD + n];
    ushort hi = f2bf(v);
    H[slot * 8 + j] = hi;
    L[slot * 8 + j] = f2bf(v - bf2f(hi));
  }
}

// ---------------------------------------------------------------------------
// node GEMM (fp32 VALU, unchanged — validated)
// ---------------------------------------------------------------------------
__global__ __launch_bounds__(256)
void node_gemm(const float* __restrict__ A1, int K1,
               const float* __restrict__ A2, int K2,
               const float* __restrict__ scale,
               const float* __restrict__ W,
               const float* __restrict__ bias,
               float* __restrict__ C, int M, int act)
{
  __shared__ float sA[64 * 36];
  __shared__ float sB[32 * 256];
  __shared__ float sBias[256];
  const int tid = threadIdx.x;
  const int r0  = blockIdx.x * 64;
  if (bias) sBias[tid] = bias[tid];
  const int ty = tid >> 4, tx = tid & 15;

  float acc[4][16];
#pragma unroll
  for (int r = 0; r < 4; r++)
#pragma unroll
    for (int c = 0; c < 16; c++) acc[r][c] = 0.f;

  const int K = K1 + K2;
  const int arow = tid >> 2;
  const int aks  = (tid & 3) * 8;
  const int gr_a = r0 + arow;

  for (int kb = 0; kb < K; kb += 32) {
    const float* Ap; int lda, koff; float sc = 1.0f;
    if (kb < K1) { Ap = A1; lda = K1; koff = kb; }
    else { Ap = A2; lda = K2; koff = kb - K1;
           if (scale) sc = scale[gr_a < M ? gr_a : M - 1]; }
#pragma unroll
    for (int j = 0; j < 8; j += 4) {
      float4 v;
      if (gr_a < M) v = *(const float4*)&Ap[(long)gr_a * lda + koff + aks + j];
      else { v.x = v.y = v.z = v.w = 0.f; }
      v.x *= sc; v.y *= sc; v.z *= sc; v.w *= sc;
      *(float4*)&sA[arow * 36 + aks + j] = v;
    }
#pragma unroll
    for (int j = 0; j < 8; j++) {
      int i = tid + 256 * j, row = i >> 6, c4 = i & 63;
      *(float4*)&sB[row * HD + c4 * 4] = *(const float4*)&W[(long)(kb + row) * HD + c4 * 4];
    }
    __syncthreads();
#pragma unroll 4
    for (int kk = 0; kk < 32; kk++) {
      float a0 = sA[(ty * 4 + 0) * 36 + kk];
      float a1 = sA[(ty * 4 + 1) * 36 + kk];
      float a2 = sA[(ty * 4 + 2) * 36 + kk];
      float a3 = sA[(ty * 4 + 3) * 36 + kk];
#pragma unroll
      for (int c = 0; c < 16; c++) {
        float b = sB[kk * HD + tx + 16 * c];
        acc[0][c] += a0 * b; acc[1][c] += a1 * b;
        acc[2][c] += a2 * b; acc[3][c] += a3 * b;
      }
    }
    __syncthreads();
  }

#pragma unroll
  for (int r = 0; r < 4; r++) {
    int gr = r0 + ty * 4 + r;
    if (gr >= M) continue;
#pragma unroll
    for (int c = 0; c < 16; c++) {
      int col = tx + 16 * c;
      float v = acc[r][c];
      if (bias) v += sBias[col];
      if (act)  v = fmaxf(v, 0.f);
      C[(long)gr * HD + col] = v;
    }
  }
}

// out[j] = base[j] + sum_k (v1[k] + v2?[k]) * W[k][j]
__global__ __launch_bounds__(256)
void bias_fold_k(const float* __restrict__ v1, const float* __restrict__ v2,
                 const float* __restrict__ W, const float* __restrict__ base,
                 float* __restrict__ out)
{
  const int j = threadIdx.x;
  float s = base[j];
  for (int k = 0; k < HD; k++) {
    float v = v1[k] + (v2 ? v2[k] : 0.f);
    s += v * W[k * HD + j];
  }
  out[j] = s;
}

__global__ void rdeg_k(float* __restrict__ deg)
{
  int i = blockIdx.x * blockDim.x + threadIdx.x;
  if (i < N_NODES) deg[i] = 1.0f / fmaxf(deg[i], 1.0f);
}

// ---------------------------------------------------------------------------
// build_h0 (512 threads, 64 edges): h0 = relu(Ps[s]+Pd[d]+ea@W6+b0) -> Ah/Al
// 8 threads/edge (el=tid>>3, q=tid&7), 32 cols each.
// A tile LDS: bf16 [64][256] hi+lo, row stride 512B, byte^=(row&7)<<4.
// W6/b0/eattr read straight from global (L1/L2-served, validated r6).
// ---------------------------------------------------------------------------
__device__ __forceinline__ void build_h0(
    int tid, const float* __restrict__ Ps, const float* __restrict__ Pd,
    const float* __restrict__ eattr, long e0,
    const float* __restrict__ W6, const float* __restrict__ b0,
    const int* sSrc, const int* sDst, ushort* Ah, ushort* Al)
{
  const int el = tid >> 3, q = tid & 7;
  const int sv = sSrc[el], dv = sDst[el];
  const long e = e0 + el;
  float eav[6];
#pragma unroll
  for (int k = 0; k < 6; ++k) eav[k] = eattr[e * 6 + k];
  const float* ps = Ps + (long)sv * HD + q * 32;
  const float* pd = Pd + (long)dv * HD + q * 32;
  const int sw = (el & 7) << 4;
  char* ahB = (char*)Ah + el * 512;
  char* alB = (char*)Al + el * 512;
#pragma unroll
  for (int jj = 0; jj < 8; ++jj) {
    float4 a  = *(const float4*)(ps + jj * 4);
    float4 b  = *(const float4*)(pd + jj * 4);
    float4 bb = *(const float4*)(b0 + q * 32 + jj * 4);
    float vx = a.x + b.x + bb.x;
    float vy = a.y + b.y + bb.y;
    float vz = a.z + b.z + bb.z;
    float vw = a.w + b.w + bb.w;
#pragma unroll
    for (int k = 0; k < 6; ++k) {
      float4 w = *(const float4*)(W6 + k * HD + q * 32 + jj * 4);
      vx += eav[k] * w.x; vy += eav[k] * w.y;
      vz += eav[k] * w.z; vw += eav[k] * w.w;
    }
    vx = fmaxf(vx, 0.f); vy = fmaxf(vy, 0.f);
    vz = fmaxf(vz, 0.f); vw = fmaxf(vw, 0.f);
    ushort4 hh, ll;
    hh.x = f2bf(vx); hh.y = f2bf(vy); hh.z = f2bf(vz); hh.w = f2bf(vw);
    ll.x = f2bf(vx - bf2f(hh.x)); ll.y = f2bf(vy - bf2f(hh.y));
    ll.z = f2bf(vz - bf2f(hh.z)); ll.w = f2bf(vw - bf2f(hh.w));
    const int off = (q * 64 + jj * 8) ^ sw;
    *(ushort4*)(ahB + off) = hh;
    *(ushort4*)(alB + off) = ll;
  }
}

__device__ __forceinline__ void write_split(ushort* Ah, ushort* Al,
                                            int row, int col, float v)
{
  const int off = row * 512 + ((col * 2) ^ ((row & 7) << 4));
  ushort hi = f2bf(v);
  *(ushort*)((char*)Ah + off) = hi;
  *(ushort*)((char*)Al + off) = f2bf(v - bf2f(hi));
}

__device__ __forceinline__ void load_afrag(const ushort* Ah, const ushort* Al,
    int row, int s, int lane, bf16x8& ah, bf16x8& al)
{
  const int aoff = row * 512 + ((((s << 6) + ((lane >> 4) << 4))) ^ ((row & 7) << 4));
  ah = *(const bf16x8*)((const char*)Ah + aoff);
  al = *(const bf16x8*)((const char*)Al + aoff);
}

// single-B bf16x3 GEMM pass over a 64-row tile:
// wave (wrg,wc) computes rows wrg*32..+32, cols wc*64..+64 -> acc[2][4]
__device__ __forceinline__ void gemm_pass(
    const ushort* __restrict__ pW,
    const ushort* Ah, const ushort* Al,
    int lane, int wc, int wrg, f32x4 acc[2][4])
{
  const bf16x8* pH = (const bf16x8*)pW;
  const bf16x8* pL = (const bf16x8*)(pW + 65536);
#pragma unroll 2
  for (int s = 0; s < 8; ++s) {
    bf16x8 ah[2], al[2];
#pragma unroll
    for (int rb = 0; rb < 2; ++rb)
      load_afrag(Ah, Al, (wrg * 2 + rb) * 16 + (lane & 15), s, lane, ah[rb], al[rb]);
#pragma unroll
    for (int cf = 0; cf < 4; ++cf) {
      const int slot = s * 1024 + (wc * 4 + cf) * 64 + lane;
      bf16x8 bh = pH[slot];
      bf16x8 bl = pL[slot];
#pragma unroll
      for (int rb = 0; rb < 2; ++rb) {
        acc[rb][cf] = MFMA16(al[rb], bh, acc[rb][cf], 0, 0, 0);
        acc[rb][cf] = MFMA16(ah[rb], bl, acc[rb][cf], 0, 0, 0);
        acc[rb][cf] = MFMA16(ah[rb], bh, acc[rb][cf], 0, 0, 0);
      }
    }
  }
}

// ---------------------------------------------------------------------------
// conv_in edge stage: h0 -> ea1 = h0@We0b + be0b -> atomic agg/deg.
// 512 threads, 64 edges/block, ~66KB LDS -> 2 blocks/CU, 128-reg cap, no spill.
// ---------------------------------------------------------------------------
__global__ __launch_bounds__(512, 4)
void edge_conv_in(const int* __restrict__ ei, const float* __restrict__ eattr,
                  const float* __restrict__ Ps, const float* __restrict__ Pd,
                  const float* __restrict__ W6, const float* __restrict__ b0,
                  const ushort* __restrict__ pW0,
                  const float* __restrict__ be0b,
                  float* __restrict__ agg, float* __restrict__ deg)
{
  __shared__ ushort Ah[64 * 256];
  __shared__ ushort Al[64 * 256];
  __shared__ int    sSrc[64], sDst[64];
  const int tid = threadIdx.x;
  const long e0 = (long)blockIdx.x * 64;

  if (tid < 64) {
    int dv = ei[N_EDGES + e0 + tid];
    sDst[tid] = dv;
    atomicAdd(&deg[dv], 1.0f);
  } else if (tid < 128) {
    sSrc[tid - 64] = ei[e0 + tid - 64];
  }
  __syncthreads();

  build_h0(tid, Ps, Pd, eattr, e0, W6, b0, sSrc, sDst, Ah, Al);
  __syncthreads();

  const int lane = tid & 63, wid = tid >> 6;
  const int wc = wid & 3, wrg = wid >> 2;

  f32x4 acc[2][4];
#pragma unroll
  for (int rb = 0; rb < 2; ++rb)
#pragma unroll
    for (int cf = 0; cf < 4; ++cf) acc[rb][cf] = (f32x4){0.f, 0.f, 0.f, 0.f};
  gemm_pass(pW0, Ah, Al, lane, wc, wrg, acc);

#pragma unroll
  for (int rb = 0; rb < 2; ++rb) {
    const int rbase = (wrg * 2 + rb) * 16 + ((lane >> 4) << 2);
#pragma unroll
    for (int cf = 0; cf < 4; ++cf) {
      const int col = wc * 64 + cf * 16 + (lane & 15);
      const float bv = be0b[col];
#pragma unroll
      for (int r = 0; r < 4; ++r)
        atomicAdd(&agg[(long)sDst[rbase + r] * HD + col], acc[rb][cf][r] + bv);
    }
  }
}

// ---------------------------------------------------------------------------
// Fused conv[0] edge MLP + predictor (ea1 algebraically folded out):
//   h0  = relu(Ps[s]+Pd[d]+ea@W6+b0)
//   h1  = relu(h0@WA + P1s[s]+P1d[d]+bA)     WA = We0b@WeE, bA = be0b@WeE+be1a
//   t   = h0@WB                              WB = We0b@Wp1  (reg-resident)
//   z   = h1@Wc + t + bc                     Wc = We1b@Wp1, bc=(be1b+be0b)@Wp1+bp1
//   out = leaky_relu(z)@Wp2 + bp2
// 512 threads, 64 edges/block, 3 sequential single-B GEMM passes; peak live
// regs ~108 < 128 cap -> no scratch spill (the r5/r6 bug).
// ---------------------------------------------------------------------------
__global__ __launch_bounds__(512, 4)
void edge_pred(const int* __restrict__ ei, const float* __restrict__ eattr,
               const float* __restrict__ Ps, const float* __restrict__ Pd,
               const float* __restrict__ W6, const float* __restrict__ b0,
               const float* __restrict__ P1s, const float* __restrict__ P1d,
               const ushort* __restrict__ pWA, const ushort* __restrict__ pWB,
               const ushort* __restrict__ pWc,
               const float* __restrict__ bA, const float* __restrict__ bc,
               const float* __restrict__ Wp2, const float* __restrict__ bp2,
               float* __restrict__ out)
{
  __shared__ ushort Ah[64 * 256];
  __shared__ ushort Al[64 * 256];
  __shared__ float  sOut[64];
  __shared__ int    sSrc[64], sDst[64];
  const int tid = threadIdx.x;
  const long e0 = (long)blockIdx.x * 64;

  if (tid < 64) {
    sDst[tid] = ei[N_EDGES + e0 + tid];
    sOut[tid] = bp2[0];
  } else if (tid < 128) {
    sSrc[tid - 64] = ei[e0 + tid - 64];
  }
  __syncthreads();

  build_h0(tid, Ps, Pd, eattr, e0, W6, b0, sSrc, sDst, Ah, Al);
  __syncthreads();

  const int lane = tid & 63, wid = tid >> 6;
  const int wc = wid & 3, wrg = wid >> 2;

  // ---- pass 1: acc1 = h0@WA ----
  f32x4 acc1[2][4];
#pragma unroll
  for (int rb = 0; rb < 2; ++rb)
#pragma unroll
    for (int cf = 0; cf < 4; ++cf) acc1[rb][cf] = (f32x4){0.f, 0.f, 0.f, 0.f};
  gemm_pass(pWA, Ah, Al, lane, wc, wrg, acc1);

  // ---- pass 2: accT = h0@WB ----
  f32x4 accT[2][4];
#pragma unroll
  for (int rb = 0; rb < 2; ++rb)
#pragma unroll
    for (int cf = 0; cf < 4; ++cf) accT[rb][cf] = (f32x4){0.f, 0.f, 0.f, 0.f};
  gemm_pass(pWB, Ah, Al, lane, wc, wrg, accT);
  __syncthreads();   // all h0 reads complete before overwriting the A tile

  // ---- epilogue: h1 = relu(acc1 + P1s[s]+P1d[d]+bA) -> A tile ----
#pragma unroll
  for (int rb = 0; rb < 2; ++rb) {
    const int rbase = (wrg * 2 + rb) * 16 + ((lane >> 4) << 2);
#pragma unroll
    for (int cf = 0; cf < 4; ++cf) {
      const int col = wc * 64 + cf * 16 + (lane & 15);
      const float bv = bA[col];
#pragma unroll
      for (int r = 0; r < 4; ++r) {
        const int row = rbase + r;
        float v = acc1[rb][cf][r] + P1s[(long)sSrc[row] * HD + col]
                                  + P1d[(long)sDst[row] * HD + col] + bv;
        write_split(Ah, Al, row, col, fmaxf(v, 0.f));
      }
    }
  }
  __syncthreads();

  // ---- pass 3: accZ = h1@Wc ----
  f32x4 accZ[2][4];
#pragma unroll
  for (int rb = 0; rb < 2; ++rb)
#pragma unroll
    for (int cf = 0; cf < 4; ++cf) accZ[rb][cf] = (f32x4){0.f, 0.f, 0.f, 0.f};
  gemm_pass(pWc, Ah, Al, lane, wc, wrg, accZ);

  // ---- finale: z = accZ + accT + bc; leaky; dot Wp2; reduce ----
  float p[2][4] = {{0.f,0.f,0.f,0.f},{0.f,0.f,0.f,0.f}};
#pragma unroll
  for (int cf = 0; cf < 4; ++cf) {
    const int col = wc * 64 + cf * 16 + (lane & 15);
    const float w   = Wp2[col];
    const float bcv = bc[col];
#pragma unroll
    for (int rb = 0; rb < 2; ++rb)
#pragma unroll
      for (int r = 0; r < 4; ++r) {
        float z = accZ[rb][cf][r] + accT[rb][cf][r] + bcv;
        z = z > 0.f ? z : 0.01f * z;
        p[rb][r] += z * w;
      }
  }
#pragma unroll
  for (int rb = 0; rb < 2; ++rb)
#pragma unroll
    for (int r = 0; r < 4; ++r) {
      p[rb][r] += __shfl_xor(p[rb][r], 1);
      p[rb][r] += __shfl_xor(p[rb][r], 2);
      p[rb][r] += __shfl_xor(p[rb][r], 4);
      p[rb][r] += __shfl_xor(p[rb][r], 8);
    }
  if ((lane & 15) == 0) {
#pragma unroll
    for (int rb = 0; rb < 2; ++rb) {
      const int rbase = (wrg * 2 + rb) * 16 + ((lane >> 4) << 2);
#pragma unroll
      for (int r = 0; r < 4; ++r) atomicAdd(&sOut[rbase + r], p[rb][r]);
    }
  }
  __syncthreads();
  if (tid < 64) out[e0 + tid] = sOut[tid];
}

// ---------------------------------------------------------------------------
extern "C" void kernel_launch(void* const* d_in, const int* in_sizes, int n_in,
                              void* d_out, int out_size, void* d_ws, size_t ws_size,
                              hipStream_t stream)
{
  const float* x     = (const float*)d_in[0];
  const int*   ei    = (const int*)d_in[1];
  const float* eattr = (const float*)d_in[2];
  const float* We0a  = (const float*)d_in[3];
  const float* be0a  = (const float*)d_in[4];
  const float* We0b  = (const float*)d_in[5];
  const float* be0b  = (const float*)d_in[6];
  const float* Wn0a  = (const float*)d_in[7];
  const float* bn0a  = (const float*)d_in[8];
  const float* Wn0b  = (const float*)d_in[9];
  const float* bn0b  = (const float*)d_in[10];
  const float* We1a  = (const float*)d_in[11];
  const float* be1a  = (const float*)d_in[12];
  const float* We1b  = (const float*)d_in[13];
  const float* be1b  = (const float*)d_in[14];
  // d_in[15..18] dead (conv[0] node MLP never reaches the output)
  const float* Wp1   = (const float*)d_in[19];
  const float* bp1   = (const float*)d_in[20];
  const float* Wp2   = (const float*)d_in[21];
  const float* bp2   = (const float*)d_in[22];
  float* out = (float*)d_out;
  float* ws  = (float*)d_ws;

  float* P_s  = ws;
  float* P_d  = ws + OFF_PD;
  float* bufA = ws + OFF_BA;
  float* bufB = ws + OFF_BB;
  float* bufC = ws + OFF_BC;
  float* deg  = ws + OFF_DEG;
  float* bcB  = ws + OFF_BCV;
  float* bAB  = ws + OFF_BAV;
  ushort* pW0 = (ushort*)(ws + OFF_PW0);

  // composite-weight area inside bufB (dead after P1s/P1d are produced)
  float*  WAf = ws + OFF_BB;
  float*  WBf = ws + OFF_BB + 65536;
  float*  WcF = ws + OFF_BB + 131072;
  ushort* pWA = (ushort*)(ws + OFF_BB + 196608);
  ushort* pWB = (ushort*)(ws + OFF_BB + 262144);
  ushort* pWc = (ushort*)(ws + OFF_BB + 327680);

  const float* W6  = We0a + 1024 * HD;   // edge_attr rows of We0a
  const float* WeE = We1a + 512 * HD;    // ea1 rows of We1a

  // zero agg + deg (contiguous)
  hipMemsetAsync(bufC, 0, (2560000 + 10000) * sizeof(float), stream);

  const int ngrid = (N_NODES + 63) / 64;   // 157
  const int egrid = N_EDGES / 64;          // 5000

  // node projections + conv_in prep
  node_gemm<<<ngrid, 256, 0, stream>>>(x, 512, nullptr, 0, nullptr, We0a,            nullptr, P_s, N_NODES, 0);
  node_gemm<<<ngrid, 256, 0, stream>>>(x, 512, nullptr, 0, nullptr, We0a + 512 * HD, nullptr, P_d, N_NODES, 0);
  prep_split<<<32, 256, 0, stream>>>(We0b, pW0, pW0 + 65536);
  bias_fold_k<<<1, 256, 0, stream>>>(be1b, be0b, Wp1, bp1, bcB);     // bc'
  bias_fold_k<<<1, 256, 0, stream>>>(be0b, nullptr, WeE, be1a, bAB); // bA

  // conv_in edge stage -> agg, deg
  edge_conv_in<<<egrid, 512, 0, stream>>>(ei, eattr, P_s, P_d, W6, be0a,
                                          pW0, be0b, bufC, deg);
  rdeg_k<<<(N_NODES + 255) / 256, 256, 0, stream>>>(deg);

  // node pipeline
  node_gemm<<<ngrid, 256, 0, stream>>>(x, 512, bufC, 256, deg, Wn0a, bn0a, bufA, N_NODES, 1);          // t1
  node_gemm<<<ngrid, 256, 0, stream>>>(bufA, 256, nullptr, 0, nullptr, Wn0b, bn0b, bufB, N_NODES, 0);  // x1
  node_gemm<<<ngrid, 256, 0, stream>>>(bufB, 256, nullptr, 0, nullptr, We1a,            nullptr, bufA, N_NODES, 0); // P1s
  node_gemm<<<ngrid, 256, 0, stream>>>(bufB, 256, nullptr, 0, nullptr, We1a + 256 * HD, nullptr, bufC, N_NODES, 0); // P1d

  // composite weights (bufB/x1 now dead): WA=We0b@WeE, WB=We0b@Wp1, Wc=We1b@Wp1
  node_gemm<<<4, 256, 0, stream>>>(We0b, 256, nullptr, 0, nullptr, WeE, nullptr, WAf, 256, 0);
  node_gemm<<<4, 256, 0, stream>>>(We0b, 256, nullptr, 0, nullptr, Wp1, nullptr, WBf, 256, 0);
  node_gemm<<<4, 256, 0, stream>>>(We1b, 256, nullptr, 0, nullptr, Wp1, nullptr, WcF, 256, 0);
  prep_split<<<32, 256, 0, stream>>>(WAf, pWA, pWA + 65536);
  prep_split<<<32, 256, 0, stream>>>(WBf, pWB, pWB + 65536);
  prep_split<<<32, 256, 0, stream>>>(WcF, pWc, pWc + 65536);

  // fused conv[0] edge MLP + predictor
  edge_pred<<<egrid, 512, 0, stream>>>(ei, eattr, P_s, P_d, W6, be0a,
      bufA, bufC, pWA, pWB, pWc, bAB, bcB, Wp2, bp2, out);
}

// Round 8
// 2387.231 us; speedup vs baseline: 1.1206x; 1.0275x over previous
//
#include <hip/hip_runtime.h>

#define N_NODES 10000
#define N_EDGES 320000
#define HD      256

typedef __attribute__((ext_vector_type(8))) short bf16x8;
typedef __attribute__((ext_vector_type(4))) float f32x4;
#define MFMA16 __builtin_amdgcn_mfma_f32_16x16x32_bf16

// ---------------------------------------------------------------------------
// ws layout (floats), max offset 12,941,584 fl = 51.77 MB (proven r3/r5/r7)
//   P_s  @ 0           [N,256]
//   P_d  @ 2,560,000   [N,256]
//   bufA @ 5,120,000   t1 -> P1s
//   bufB @ 7,680,000   x1 -> (dead) -> WAf/WBf/WcF + pWA/pWB/pWc
//   bufC @ 10,240,000  agg -> P1d
//   deg  @ 12,800,000  [N]
//   bc   @ 12,810,000  [256]   (be1b+be0b)@Wp1 + bp1
//   bA   @ 12,810,256  [256]   be0b@WeE + be1a
//   pW0  @ 12,810,512  We0b split H|L (131,072 ushorts)
// ---------------------------------------------------------------------------
#define OFF_PD   2560000
#define OFF_BA   5120000
#define OFF_BB   7680000
#define OFF_BC   10240000
#define OFF_DEG  12800000
#define OFF_BCV  12810000
#define OFF_BAV  12810256
#define OFF_PW0  12810512

__device__ __forceinline__ ushort f2bf(float x) {
  union { float f; unsigned u; } c; c.f = x;
  unsigned r = (c.u + 0x7FFFu + ((c.u >> 16) & 1u)) >> 16;
  return (ushort)r;
}
__device__ __forceinline__ float bf2f(ushort h) {
  union { float f; unsigned u; } c; c.u = ((unsigned)h) << 16; return c.f;
}

// ---------------------------------------------------------------------------
// prep_split: W[256][256] fp32 -> fragment-linear split-bf16 H|L (validated r3)
// slot=(s*16+cfg)*64+lane holds j=0..7: W[s*32+(lane>>4)*8+j][cfg*16+(lane&15)]
// ---------------------------------------------------------------------------
__global__ __launch_bounds__(256)
void prep_split(const float* __restrict__ W, ushort* __restrict__ H,
                ushort* __restrict__ L)
{
  int slot = blockIdx.x * 256 + threadIdx.x;
  int s    = slot >> 10;
  int rem  = slot & 1023;
  int cf   = rem >> 6;
  int lane = rem & 63;
  int k0 = s * 32 + ((lane >> 4) << 3);
  int n  = cf * 16 + (lane & 15);
#pragma unroll
  for (int j = 0; j < 8; ++j) {
    float v = W[(k0 + j) * HD + n];
    ushort hi = f2bf(v);
    H[slot * 8 + j] = hi;
    L[slot * 8 + j] = f2bf(v - bf2f(hi));
  }
}

// ---------------------------------------------------------------------------
// node GEMM (fp32 VALU, unchanged — validated)
// ---------------------------------------------------------------------------
__global__ __launch_bounds__(256)
void node_gemm(const float* __restrict__ A1, int K1,
               const float* __restrict__ A2, int K2,
               const float* __restrict__ scale,
               const float* __restrict__ W,
               const float* __restrict__ bias,
               float* __restrict__ C, int M, int act)
{
  __shared__ float sA[64 * 36];
  __shared__ float sB[32 * 256];
  __shared__ float sBias[256];
  const int tid = threadIdx.x;
  const int r0  = blockIdx.x * 64;
  if (bias) sBias[tid] = bias[tid];
  const int ty = tid >> 4, tx = tid & 15;

  float acc[4][16];
#pragma unroll
  for (int r = 0; r < 4; r++)
#pragma unroll
    for (int c = 0; c < 16; c++) acc[r][c] = 0.f;

  const int K = K1 + K2;
  const int arow = tid >> 2;
  const int aks  = (tid & 3) * 8;
  const int gr_a = r0 + arow;

  for (int kb = 0; kb < K; kb += 32) {
    const float* Ap; int lda, koff; float sc = 1.0f;
    if (kb < K1) { Ap = A1; lda = K1; koff = kb; }
    else { Ap = A2; lda = K2; koff = kb - K1;
           if (scale) sc = scale[gr_a < M ? gr_a : M - 1]; }
#pragma unroll
    for (int j = 0; j < 8; j += 4) {
      float4 v;
      if (gr_a < M) v = *(const float4*)&Ap[(long)gr_a * lda + koff + aks + j];
      else { v.x = v.y = v.z = v.w = 0.f; }
      v.x *= sc; v.y *= sc; v.z *= sc; v.w *= sc;
      *(float4*)&sA[arow * 36 + aks + j] = v;
    }
#pragma unroll
    for (int j = 0; j < 8; j++) {
      int i = tid + 256 * j, row = i >> 6, c4 = i & 63;
      *(float4*)&sB[row * HD + c4 * 4] = *(const float4*)&W[(long)(kb + row) * HD + c4 * 4];
    }
    __syncthreads();
#pragma unroll 4
    for (int kk = 0; kk < 32; kk++) {
      float a0 = sA[(ty * 4 + 0) * 36 + kk];
      float a1 = sA[(ty * 4 + 1) * 36 + kk];
      float a2 = sA[(ty * 4 + 2) * 36 + kk];
      float a3 = sA[(ty * 4 + 3) * 36 + kk];
#pragma unroll
      for (int c = 0; c < 16; c++) {
        float b = sB[kk * HD + tx + 16 * c];
        acc[0][c] += a0 * b; acc[1][c] += a1 * b;
        acc[2][c] += a2 * b; acc[3][c] += a3 * b;
      }
    }
    __syncthreads();
  }

#pragma unroll
  for (int r = 0; r < 4; r++) {
    int gr = r0 + ty * 4 + r;
    if (gr >= M) continue;
#pragma unroll
    for (int c = 0; c < 16; c++) {
      int col = tx + 16 * c;
      float v = acc[r][c];
      if (bias) v += sBias[col];
      if (act)  v = fmaxf(v, 0.f);
      C[(long)gr * HD + col] = v;
    }
  }
}

// out[j] = base[j] + sum_k (v1[k] + v2?[k]) * W[k][j]
__global__ __launch_bounds__(256)
void bias_fold_k(const float* __restrict__ v1, const float* __restrict__ v2,
                 const float* __restrict__ W, const float* __restrict__ base,
                 float* __restrict__ out)
{
  const int j = threadIdx.x;
  float s = base[j];
  for (int k = 0; k < HD; k++) {
    float v = v1[k] + (v2 ? v2[k] : 0.f);
    s += v * W[k * HD + j];
  }
  out[j] = s;
}

__global__ void rdeg_k(float* __restrict__ deg)
{
  int i = blockIdx.x * blockDim.x + threadIdx.x;
  if (i < N_NODES) deg[i] = 1.0f / fmaxf(deg[i], 1.0f);
}

// ---------------------------------------------------------------------------
// build_h0 (512 threads, 64 edges): h0 = relu(Ps[s]+Pd[d]+ea@W6+b0) -> Ah/Al
// 8 threads/edge (el=tid>>3, q=tid&7), 32 cols each.
// A tile LDS: bf16 [64][256] hi+lo, row stride 512B, byte^=(row&7)<<4.
// ---------------------------------------------------------------------------
__device__ __forceinline__ void build_h0(
    int tid, const float* __restrict__ Ps, const float* __restrict__ Pd,
    const float* __restrict__ eattr, long e0,
    const float* __restrict__ W6, const float* __restrict__ b0,
    const int* sSrc, const int* sDst, ushort* Ah, ushort* Al)
{
  const int el = tid >> 3, q = tid & 7;
  const int sv = sSrc[el], dv = sDst[el];
  const long e = e0 + el;
  float eav[6];
#pragma unroll
  for (int k = 0; k < 6; ++k) eav[k] = eattr[e * 6 + k];
  const float* ps = Ps + (long)sv * HD + q * 32;
  const float* pd = Pd + (long)dv * HD + q * 32;
  const int sw = (el & 7) << 4;
  char* ahB = (char*)Ah + el * 512;
  char* alB = (char*)Al + el * 512;
#pragma unroll
  for (int jj = 0; jj < 8; ++jj) {
    float4 a  = *(const float4*)(ps + jj * 4);
    float4 b  = *(const float4*)(pd + jj * 4);
    float4 bb = *(const float4*)(b0 + q * 32 + jj * 4);
    float vx = a.x + b.x + bb.x;
    float vy = a.y + b.y + bb.y;
    float vz = a.z + b.z + bb.z;
    float vw = a.w + b.w + bb.w;
#pragma unroll
    for (int k = 0; k < 6; ++k) {
      float4 w = *(const float4*)(W6 + k * HD + q * 32 + jj * 4);
      vx += eav[k] * w.x; vy += eav[k] * w.y;
      vz += eav[k] * w.z; vw += eav[k] * w.w;
    }
    vx = fmaxf(vx, 0.f); vy = fmaxf(vy, 0.f);
    vz = fmaxf(vz, 0.f); vw = fmaxf(vw, 0.f);
    ushort4 hh, ll;
    hh.x = f2bf(vx); hh.y = f2bf(vy); hh.z = f2bf(vz); hh.w = f2bf(vw);
    ll.x = f2bf(vx - bf2f(hh.x)); ll.y = f2bf(vy - bf2f(hh.y));
    ll.z = f2bf(vz - bf2f(hh.z)); ll.w = f2bf(vw - bf2f(hh.w));
    const int off = (q * 64 + jj * 8) ^ sw;
    *(ushort4*)(ahB + off) = hh;
    *(ushort4*)(alB + off) = ll;
  }
}

__device__ __forceinline__ void write_split(ushort* Ah, ushort* Al,
                                            int row, int col, float v)
{
  const int off = row * 512 + ((col * 2) ^ ((row & 7) << 4));
  ushort hi = f2bf(v);
  *(ushort*)((char*)Ah + off) = hi;
  *(ushort*)((char*)Al + off) = f2bf(v - bf2f(hi));
}

__device__ __forceinline__ void load_afrag(const ushort* Ah, const ushort* Al,
    int row, int s, int lane, bf16x8& ah, bf16x8& al)
{
  const int aoff = row * 512 + ((((s << 6) + ((lane >> 4) << 4))) ^ ((row & 7) << 4));
  ah = *(const bf16x8*)((const char*)Ah + aoff);
  al = *(const bf16x8*)((const char*)Al + aoff);
}

// ---------------------------------------------------------------------------
// single-B bf16x3 GEMM pass, wave tile 64 rows x 32 cols (rb=0..3, cf=0..1).
// Each B fragment fetched exactly once per block per pass (no wrg redundancy).
// B frags double-buffered in registers: s+1 loads issued before s's MFMAs.
// ---------------------------------------------------------------------------
__device__ __forceinline__ void gemm_pass(
    const ushort* __restrict__ pW,
    const ushort* Ah, const ushort* Al,
    int lane, int wid, f32x4 acc[4][2])
{
  const bf16x8* pH = (const bf16x8*)pW;
  const bf16x8* pL = (const bf16x8*)(pW + 65536);
  const int cbase = wid * 2 * 64 + lane;    // cfg = wid*2+cf
  bf16x8 bh[2], bl[2];
#pragma unroll
  for (int cf = 0; cf < 2; ++cf) {
    bh[cf] = pH[cbase + cf * 64];
    bl[cf] = pL[cbase + cf * 64];
  }
#pragma unroll
  for (int s = 0; s < 8; ++s) {
    bf16x8 nbh[2], nbl[2];
    if (s < 7) {
      const int slotn = (s + 1) * 1024 + cbase;
#pragma unroll
      for (int cf = 0; cf < 2; ++cf) {
        nbh[cf] = pH[slotn + cf * 64];
        nbl[cf] = pL[slotn + cf * 64];
      }
    }
    bf16x8 ah[4], al[4];
#pragma unroll
    for (int rb = 0; rb < 4; ++rb)
      load_afrag(Ah, Al, rb * 16 + (lane & 15), s, lane, ah[rb], al[rb]);
#pragma unroll
    for (int cf = 0; cf < 2; ++cf)
#pragma unroll
      for (int rb = 0; rb < 4; ++rb) {
        acc[rb][cf] = MFMA16(al[rb], bh[cf], acc[rb][cf], 0, 0, 0);
        acc[rb][cf] = MFMA16(ah[rb], bl[cf], acc[rb][cf], 0, 0, 0);
        acc[rb][cf] = MFMA16(ah[rb], bh[cf], acc[rb][cf], 0, 0, 0);
      }
    if (s < 7) {
#pragma unroll
      for (int cf = 0; cf < 2; ++cf) { bh[cf] = nbh[cf]; bl[cf] = nbl[cf]; }
    }
  }
}

// ---------------------------------------------------------------------------
// conv_in edge stage: h0 -> ea1 = h0@We0b + be0b -> atomic agg/deg.
// 512 threads, 64 edges/block, 66KB LDS -> 2 blocks/CU, no spill.
// ---------------------------------------------------------------------------
__global__ __launch_bounds__(512, 4)
void edge_conv_in(const int* __restrict__ ei, const float* __restrict__ eattr,
                  const float* __restrict__ Ps, const float* __restrict__ Pd,
                  const float* __restrict__ W6, const float* __restrict__ b0,
                  const ushort* __restrict__ pW0,
                  const float* __restrict__ be0b,
                  float* __restrict__ agg, float* __restrict__ deg)
{
  __shared__ ushort Ah[64 * 256];
  __shared__ ushort Al[64 * 256];
  __shared__ int    sSrc[64], sDst[64];
  const int tid = threadIdx.x;
  const long e0 = (long)blockIdx.x * 64;

  if (tid < 64) {
    int dv = ei[N_EDGES + e0 + tid];
    sDst[tid] = dv;
    atomicAdd(&deg[dv], 1.0f);
  } else if (tid < 128) {
    sSrc[tid - 64] = ei[e0 + tid - 64];
  }
  __syncthreads();

  build_h0(tid, Ps, Pd, eattr, e0, W6, b0, sSrc, sDst, Ah, Al);
  __syncthreads();

  const int lane = tid & 63, wid = tid >> 6;

  f32x4 acc[4][2];
#pragma unroll
  for (int rb = 0; rb < 4; ++rb)
#pragma unroll
    for (int cf = 0; cf < 2; ++cf) acc[rb][cf] = (f32x4){0.f, 0.f, 0.f, 0.f};
  gemm_pass(pW0, Ah, Al, lane, wid, acc);

#pragma unroll
  for (int rb = 0; rb < 4; ++rb) {
    const int rbase = rb * 16 + ((lane >> 4) << 2);
#pragma unroll
    for (int cf = 0; cf < 2; ++cf) {
      const int col = wid * 32 + cf * 16 + (lane & 15);
      const float bv = be0b[col];
#pragma unroll
      for (int r = 0; r < 4; ++r)
        atomicAdd(&agg[(long)sDst[rbase + r] * HD + col], acc[rb][cf][r] + bv);
    }
  }
}

// ---------------------------------------------------------------------------
// Fused conv[0] edge MLP + predictor (ea1 algebraically folded out):
//   h0  = relu(Ps[s]+Pd[d]+ea@W6+b0)
//   h1  = relu(h0@WA + P1s[s]+P1d[d]+bA)     WA = We0b@WeE, bA = be0b@WeE+be1a
//   t   = h0@WB                              WB = We0b@Wp1  (reg-resident)
//   z   = h1@Wc + t + bc                     Wc = We1b@Wp1, bc=(be1b+be0b)@Wp1+bp1
//   out = leaky_relu(z)@Wp2 + bp2
// 512 threads, 64 edges/block, 3 sequential single-B passes, 64x32 wave tiles.
// ---------------------------------------------------------------------------
__global__ __launch_bounds__(512, 4)
void edge_pred(const int* __restrict__ ei, const float* __restrict__ eattr,
               const float* __restrict__ Ps, const float* __restrict__ Pd,
               const float* __restrict__ W6, const float* __restrict__ b0,
               const float* __restrict__ P1s, const float* __restrict__ P1d,
               const ushort* __restrict__ pWA, const ushort* __restrict__ pWB,
               const ushort* __restrict__ pWc,
               const float* __restrict__ bA, const float* __restrict__ bc,
               const float* __restrict__ Wp2, const float* __restrict__ bp2,
               float* __restrict__ out)
{
  __shared__ ushort Ah[64 * 256];
  __shared__ ushort Al[64 * 256];
  __shared__ float  sOut[64];
  __shared__ int    sSrc[64], sDst[64];
  const int tid = threadIdx.x;
  const long e0 = (long)blockIdx.x * 64;

  if (tid < 64) {
    sDst[tid] = ei[N_EDGES + e0 + tid];
    sOut[tid] = bp2[0];
  } else if (tid < 128) {
    sSrc[tid - 64] = ei[e0 + tid - 64];
  }
  __syncthreads();

  build_h0(tid, Ps, Pd, eattr, e0, W6, b0, sSrc, sDst, Ah, Al);
  __syncthreads();

  const int lane = tid & 63, wid = tid >> 6;

  // ---- pass 1: acc1 = h0@WA ----
  f32x4 acc1[4][2];
#pragma unroll
  for (int rb = 0; rb < 4; ++rb)
#pragma unroll
    for (int cf = 0; cf < 2; ++cf) acc1[rb][cf] = (f32x4){0.f, 0.f, 0.f, 0.f};
  gemm_pass(pWA, Ah, Al, lane, wid, acc1);

  // ---- pass 2: accT = h0@WB ----
  f32x4 accT[4][2];
#pragma unroll
  for (int rb = 0; rb < 4; ++rb)
#pragma unroll
    for (int cf = 0; cf < 2; ++cf) accT[rb][cf] = (f32x4){0.f, 0.f, 0.f, 0.f};
  gemm_pass(pWB, Ah, Al, lane, wid, accT);
  __syncthreads();   // all h0 reads complete before overwriting the A tile

  // ---- epilogue: h1 = relu(acc1 + P1s[s]+P1d[d]+bA) -> A tile ----
#pragma unroll
  for (int rb = 0; rb < 4; ++rb) {
    const int rbase = rb * 16 + ((lane >> 4) << 2);
#pragma unroll
    for (int cf = 0; cf < 2; ++cf) {
      const int col = wid * 32 + cf * 16 + (lane & 15);
      const float bv = bA[col];
#pragma unroll
      for (int r = 0; r < 4; ++r) {
        const int row = rbase + r;
        float v = acc1[rb][cf][r] + P1s[(long)sSrc[row] * HD + col]
                                  + P1d[(long)sDst[row] * HD + col] + bv;
        write_split(Ah, Al, row, col, fmaxf(v, 0.f));
      }
    }
  }
  __syncthreads();

  // ---- pass 3: accZ = h1@Wc ----
  f32x4 accZ[4][2];
#pragma unroll
  for (int rb = 0; rb < 4; ++rb)
#pragma unroll
    for (int cf = 0; cf < 2; ++cf) accZ[rb][cf] = (f32x4){0.f, 0.f, 0.f, 0.f};
  gemm_pass(pWc, Ah, Al, lane, wid, accZ);

  // ---- finale: z = accZ + accT + bc; leaky; dot Wp2; reduce ----
  float p[4][4];
#pragma unroll
  for (int rb = 0; rb < 4; ++rb)
#pragma unroll
    for (int r = 0; r < 4; ++r) p[rb][r] = 0.f;
#pragma unroll
  for (int cf = 0; cf < 2; ++cf) {
    const int col = wid * 32 + cf * 16 + (lane & 15);
    const float w   = Wp2[col];
    const float bcv = bc[col];
#pragma unroll
    for (int rb = 0; rb < 4; ++rb)
#pragma unroll
      for (int r = 0; r < 4; ++r) {
        float z = accZ[rb][cf][r] + accT[rb][cf][r] + bcv;
        z = z > 0.f ? z : 0.01f * z;
        p[rb][r] += z * w;
      }
  }
#pragma unroll
  for (int rb = 0; rb < 4; ++rb)
#pragma unroll
    for (int r = 0; r < 4; ++r) {
      p[rb][r] += __shfl_xor(p[rb][r], 1);
      p[rb][r] += __shfl_xor(p[rb][r], 2);
      p[rb][r] += __shfl_xor(p[rb][r], 4);
      p[rb][r] += __shfl_xor(p[rb][r], 8);
    }
  if ((lane & 15) == 0) {
#pragma unroll
    for (int rb = 0; rb < 4; ++rb) {
      const int rbase = rb * 16 + ((lane >> 4) << 2);
#pragma unroll
      for (int r = 0; r < 4; ++r) atomicAdd(&sOut[rbase + r], p[rb][r]);
    }
  }
  __syncthreads();
  if (tid < 64) out[e0 + tid] = sOut[tid];
}

// ---------------------------------------------------------------------------
extern "C" void kernel_launch(void* const* d_in, const int* in_sizes, int n_in,
                              void* d_out, int out_size, void* d_ws, size_t ws_size,
                              hipStream_t stream)
{
  const float* x     = (const float*)d_in[0];
  const int*   ei    = (const int*)d_in[1];
  const float* eattr = (const float*)d_in[2];
  const float* We0a  = (const float*)d_in[3];
  const float* be0a  = (const float*)d_in[4];
  const float* We0b  = (const float*)d_in[5];
  const float* be0b  = (const float*)d_in[6];
  const float* Wn0a  = (const float*)d_in[7];
  const float* bn0a  = (const float*)d_in[8];
  const float* Wn0b  = (const float*)d_in[9];
  const float* bn0b  = (const float*)d_in[10];
  const float* We1a  = (const float*)d_in[11];
  const float* be1a  = (const float*)d_in[12];
  const float* We1b  = (const float*)d_in[13];
  const float* be1b  = (const float*)d_in[14];
  // d_in[15..18] dead (conv[0] node MLP never reaches the output)
  const float* Wp1   = (const float*)d_in[19];
  const float* bp1   = (const float*)d_in[20];
  const float* Wp2   = (const float*)d_in[21];
  const float* bp2   = (const float*)d_in[22];
  float* out = (float*)d_out;
  float* ws  = (float*)d_ws;

  float* P_s  = ws;
  float* P_d  = ws + OFF_PD;
  float* bufA = ws + OFF_BA;
  float* bufB = ws + OFF_BB;
  float* bufC = ws + OFF_BC;
  float* deg  = ws + OFF_DEG;
  float* bcB  = ws + OFF_BCV;
  float* bAB  = ws + OFF_BAV;
  ushort* pW0 = (ushort*)(ws + OFF_PW0);

  // composite-weight area inside bufB (dead after P1s/P1d are produced)
  float*  WAf = ws + OFF_BB;
  float*  WBf = ws + OFF_BB + 65536;
  float*  WcF = ws + OFF_BB + 131072;
  ushort* pWA = (ushort*)(ws + OFF_BB + 196608);
  ushort* pWB = (ushort*)(ws + OFF_BB + 262144);
  ushort* pWc = (ushort*)(ws + OFF_BB + 327680);

  const float* W6  = We0a + 1024 * HD;   // edge_attr rows of We0a
  const float* WeE = We1a + 512 * HD;    // ea1 rows of We1a

  // zero agg + deg (contiguous)
  hipMemsetAsync(bufC, 0, (2560000 + 10000) * sizeof(float), stream);

  const int ngrid = (N_NODES + 63) / 64;   // 157
  const int egrid = N_EDGES / 64;          // 5000

  // node projections + conv_in prep
  node_gemm<<<ngrid, 256, 0, stream>>>(x, 512, nullptr, 0, nullptr, We0a,            nullptr, P_s, N_NODES, 0);
  node_gemm<<<ngrid, 256, 0, stream>>>(x, 512, nullptr, 0, nullptr, We0a + 512 * HD, nullptr, P_d, N_NODES, 0);
  prep_split<<<32, 256, 0, stream>>>(We0b, pW0, pW0 + 65536);
  bias_fold_k<<<1, 256, 0, stream>>>(be1b, be0b, Wp1, bp1, bcB);     // bc'
  bias_fold_k<<<1, 256, 0, stream>>>(be0b, nullptr, WeE, be1a, bAB); // bA

  // conv_in edge stage -> agg, deg
  edge_conv_in<<<egrid, 512, 0, stream>>>(ei, eattr, P_s, P_d, W6, be0a,
                                          pW0, be0b, bufC, deg);
  rdeg_k<<<(N_NODES + 255) / 256, 256, 0, stream>>>(deg);

  // node pipeline
  node_gemm<<<ngrid, 256, 0, stream>>>(x, 512, bufC, 256, deg, Wn0a, bn0a, bufA, N_NODES, 1);          // t1
  node_gemm<<<ngrid, 256, 0, stream>>>(bufA, 256, nullptr, 0, nullptr, Wn0b, bn0b, bufB, N_NODES, 0);  // x1
  node_gemm<<<ngrid, 256, 0, stream>>>(bufB, 256, nullptr, 0, nullptr, We1a,            nullptr, bufA, N_NODES, 0); // P1s
  node_gemm<<<ngrid, 256, 0, stream>>>(bufB, 256, nullptr, 0, nullptr, We1a + 256 * HD, nullptr, bufC, N_NODES, 0); // P1d

  // composite weights (bufB/x1 now dead): WA=We0b@WeE, WB=We0b@Wp1, Wc=We1b@Wp1
  node_gemm<<<4, 256, 0, stream>>>(We0b, 256, nullptr, 0, nullptr, WeE, nullptr, WAf, 256, 0);
  node_gemm<<<4, 256, 0, stream>>>(We0b, 256, nullptr, 0, nullptr, Wp1, nullptr, WBf, 256, 0);
  node_gemm<<<4, 256, 0, stream>>>(We1b, 256, nullptr, 0, nullptr, Wp1, nullptr, WcF, 256, 0);
  prep_split<<<32, 256, 0, stream>>>(WAf, pWA, pWA + 65536);
  prep_split<<<32, 256, 0, stream>>>(WBf, pWB, pWB + 65536);
  prep_split<<<32, 256, 0, stream>>>(WcF, pWc, pWc + 65536);

  // fused conv[0] edge MLP + predictor
  edge_pred<<<egrid, 512, 0, stream>>>(ei, eattr, P_s, P_d, W6, be0a,
      bufA, bufC, pWA, pWB, pWc, bAB, bcB, Wp2, bp2, out);
}

// Round 10
// 2070.097 us; speedup vs baseline: 1.2923x; 1.1532x over previous
//
#include <hip/hip_runtime.h>

#define N_NODES 10000
#define N_EDGES 320000
#define HD      256

typedef __attribute__((ext_vector_type(8))) short bf16x8;
typedef __attribute__((ext_vector_type(4))) float f32x4;
#define MFMA16 __builtin_amdgcn_mfma_f32_16x16x32_bf16

// ---------------------------------------------------------------------------
// ws layout (floats), max offset 12,941,584 fl = 51.77 MB (proven r3/r5/r7/r8)
//   P_s  @ 0           [N,256]
//   P_d  @ 2,560,000   [N,256]
//   bufA @ 5,120,000   t1 -> P1s
//   bufB @ 7,680,000   x1 -> (dead) -> WAf/WBf/WcF + pWA/pWB/pWc
//   bufC @ 10,240,000  agg -> P1d
//   deg  @ 12,800,000  [N]
//   bc   @ 12,810,000  [256]   (be1b+be0b)@Wp1 + bp1
//   bA   @ 12,810,256  [256]   be0b@WeE + be1a
//   pW0  @ 12,810,512  We0b split H|L (131,072 ushorts)
// ---------------------------------------------------------------------------
#define OFF_PD   2560000
#define OFF_BA   5120000
#define OFF_BB   7680000
#define OFF_BC   10240000
#define OFF_DEG  12800000
#define OFF_BCV  12810000
#define OFF_BAV  12810256
#define OFF_PW0  12810512

__device__ __forceinline__ ushort f2bf(float x) {
  union { float f; unsigned u; } c; c.f = x;
  unsigned r = (c.u + 0x7FFFu + ((c.u >> 16) & 1u)) >> 16;
  return (ushort)r;
}
__device__ __forceinline__ float bf2f(ushort h) {
  union { float f; unsigned u; } c; c.u = ((unsigned)h) << 16; return c.f;
}

// ---------------------------------------------------------------------------
// prep_split: W[256][256] fp32 -> fragment-linear split-bf16 H|L (validated r3)
// slot=(s*16+cfg)*64+lane holds j=0..7: W[s*32+(lane>>4)*8+j][cfg*16+(lane&15)]
// ---------------------------------------------------------------------------
__global__ __launch_bounds__(256)
void prep_split(const float* __restrict__ W, ushort* __restrict__ H,
                ushort* __restrict__ L)
{
  int slot = blockIdx.x * 256 + threadIdx.x;
  int s    = slot >> 10;
  int rem  = slot & 1023;
  int cf   = rem >> 6;
  int lane = rem & 63;
  int k0 = s * 32 + ((lane >> 4) << 3);
  int n  = cf * 16 + (lane & 15);
#pragma unroll
  for (int j = 0; j < 8; ++j) {
    float v = W[(k0 + j) * HD + n];
    ushort hi = f2bf(v);
    H[slot * 8 + j] = hi;
    L[slot * 8 + j] = f2bf(v - bf2f(hi));
  }
}

// ---------------------------------------------------------------------------
// node GEMM (fp32 VALU). blockIdx.y==1 selects the (Wy,Cy) pair member, so two
// independent GEMMs sharing the same A run as one launch (2x grid fill).
// ---------------------------------------------------------------------------
__global__ __launch_bounds__(256)
void node_gemm(const float* __restrict__ A1, int K1,
               const float* __restrict__ A2, int K2,
               const float* __restrict__ scale,
               const float* __restrict__ W0,
               const float* __restrict__ bias,
               float* __restrict__ C0, int M, int act,
               const float* __restrict__ Wy, float* __restrict__ Cy)
{
  __shared__ float sA[64 * 36];
  __shared__ float sB[32 * 256];
  __shared__ float sBias[256];
  const float* W = (blockIdx.y && Wy) ? Wy : W0;
  float*       C = (blockIdx.y && Cy) ? Cy : C0;
  const int tid = threadIdx.x;
  const int r0  = blockIdx.x * 64;
  if (bias) sBias[tid] = bias[tid];
  const int ty = tid >> 4, tx = tid & 15;

  float acc[4][16];
#pragma unroll
  for (int r = 0; r < 4; r++)
#pragma unroll
    for (int c = 0; c < 16; c++) acc[r][c] = 0.f;

  const int K = K1 + K2;
  const int arow = tid >> 2;
  const int aks  = (tid & 3) * 8;
  const int gr_a = r0 + arow;

  for (int kb = 0; kb < K; kb += 32) {
    const float* Ap; int lda, koff; float sc = 1.0f;
    if (kb < K1) { Ap = A1; lda = K1; koff = kb; }
    else { Ap = A2; lda = K2; koff = kb - K1;
           if (scale) sc = scale[gr_a < M ? gr_a : M - 1]; }
#pragma unroll
    for (int j = 0; j < 8; j += 4) {
      float4 v;
      if (gr_a < M) v = *(const float4*)&Ap[(long)gr_a * lda + koff + aks + j];
      else { v.x = v.y = v.z = v.w = 0.f; }
      v.x *= sc; v.y *= sc; v.z *= sc; v.w *= sc;
      *(float4*)&sA[arow * 36 + aks + j] = v;
    }
#pragma unroll
    for (int j = 0; j < 8; j++) {
      int i = tid + 256 * j, row = i >> 6, c4 = i & 63;
      *(float4*)&sB[row * HD + c4 * 4] = *(const float4*)&W[(long)(kb + row) * HD + c4 * 4];
    }
    __syncthreads();
#pragma unroll 4
    for (int kk = 0; kk < 32; kk++) {
      float a0 = sA[(ty * 4 + 0) * 36 + kk];
      float a1 = sA[(ty * 4 + 1) * 36 + kk];
      float a2 = sA[(ty * 4 + 2) * 36 + kk];
      float a3 = sA[(ty * 4 + 3) * 36 + kk];
#pragma unroll
      for (int c = 0; c < 16; c++) {
        float b = sB[kk * HD + tx + 16 * c];
        acc[0][c] += a0 * b; acc[1][c] += a1 * b;
        acc[2][c] += a2 * b; acc[3][c] += a3 * b;
      }
    }
    __syncthreads();
  }

#pragma unroll
  for (int r = 0; r < 4; r++) {
    int gr = r0 + ty * 4 + r;
    if (gr >= M) continue;
#pragma unroll
    for (int c = 0; c < 16; c++) {
      int col = tx + 16 * c;
      float v = acc[r][c];
      if (bias) v += sBias[col];
      if (act)  v = fmaxf(v, 0.f);
      C[(long)gr * HD + col] = v;
    }
  }
}

// out[j] = base[j] + sum_k (v1[k] + v2?[k]) * W[k][j]
__global__ __launch_bounds__(256)
void bias_fold_k(const float* __restrict__ v1, const float* __restrict__ v2,
                 const float* __restrict__ W, const float* __restrict__ base,
                 float* __restrict__ out)
{
  const int j = threadIdx.x;
  float s = base[j];
  for (int k = 0; k < HD; k++) {
    float v = v1[k] + (v2 ? v2[k] : 0.f);
    s += v * W[k * HD + j];
  }
  out[j] = s;
}

__global__ void rdeg_k(float* __restrict__ deg)
{
  int i = blockIdx.x * blockDim.x + threadIdx.x;
  if (i < N_NODES) deg[i] = 1.0f / fmaxf(deg[i], 1.0f);
}

// ---------------------------------------------------------------------------
// build_h0 (512 threads, 64 edges): h0 = relu(Ps[s]+Pd[d]+ea@W6+b0) -> Ah/Al
// 8 threads/edge (el=tid>>3, q=tid&7), 32 cols each.
// A tile LDS: bf16 [64][256] hi+lo, row stride 512B, byte^=(row&7)<<4.
// ---------------------------------------------------------------------------
__device__ __forceinline__ void build_h0(
    int tid, const float* __restrict__ Ps, const float* __restrict__ Pd,
    const float* __restrict__ eattr, long e0,
    const float* __restrict__ W6, const float* __restrict__ b0,
    const int* sSrc, const int* sDst, ushort* Ah, ushort* Al)
{
  const int el = tid >> 3, q = tid & 7;
  const int sv = sSrc[el], dv = sDst[el];
  const long e = e0 + el;
  float eav[6];
#pragma unroll
  for (int k = 0; k < 6; ++k) eav[k] = eattr[e * 6 + k];
  const float* ps = Ps + (long)sv * HD + q * 32;
  const float* pd = Pd + (long)dv * HD + q * 32;
  const int sw = (el & 7) << 4;
  char* ahB = (char*)Ah + el * 512;
  char* alB = (char*)Al + el * 512;
#pragma unroll
  for (int jj = 0; jj < 8; ++jj) {
    float4 a  = *(const float4*)(ps + jj * 4);
    float4 b  = *(const float4*)(pd + jj * 4);
    float4 bb = *(const float4*)(b0 + q * 32 + jj * 4);
    float vx = a.x + b.x + bb.x;
    float vy = a.y + b.y + bb.y;
    float vz = a.z + b.z + bb.z;
    float vw = a.w + b.w + bb.w;
#pragma unroll
    for (int k = 0; k < 6; ++k) {
      float4 w = *(const float4*)(W6 + k * HD + q * 32 + jj * 4);
      vx += eav[k] * w.x; vy += eav[k] * w.y;
      vz += eav[k] * w.z; vw += eav[k] * w.w;
    }
    vx = fmaxf(vx, 0.f); vy = fmaxf(vy, 0.f);
    vz = fmaxf(vz, 0.f); vw = fmaxf(vw, 0.f);
    ushort4 hh, ll;
    hh.x = f2bf(vx); hh.y = f2bf(vy); hh.z = f2bf(vz); hh.w = f2bf(vw);
    ll.x = f2bf(vx - bf2f(hh.x)); ll.y = f2bf(vy - bf2f(hh.y));
    ll.z = f2bf(vz - bf2f(hh.z)); ll.w = f2bf(vw - bf2f(hh.w));
    const int off = (q * 64 + jj * 8) ^ sw;
    *(ushort4*)(ahB + off) = hh;
    *(ushort4*)(alB + off) = ll;
  }
}

__device__ __forceinline__ void write_split(ushort* Ah, ushort* Al,
                                            int row, int col, float v)
{
  const int off = row * 512 + ((col * 2) ^ ((row & 7) << 4));
  ushort hi = f2bf(v);
  *(ushort*)((char*)Ah + off) = hi;
  *(ushort*)((char*)Al + off) = f2bf(v - bf2f(hi));
}

__device__ __forceinline__ void load_afrag(const ushort* Ah, const ushort* Al,
    int row, int s, int lane, bf16x8& ah, bf16x8& al)
{
  const int aoff = row * 512 + ((((s << 6) + ((lane >> 4) << 4))) ^ ((row & 7) << 4));
  ah = *(const bf16x8*)((const char*)Ah + aoff);
  al = *(const bf16x8*)((const char*)Al + aoff);
}

// ---------------------------------------------------------------------------
// single-B bf16x3 GEMM pass, wave tile 64 rows x 32 cols (rb=0..3, cf=0..1).
// Each B fragment fetched exactly once per block per pass. NO explicit B
// double-buffer (r8 spilled: 313MB scratch). A frags loaded per-rb to keep
// live registers ~105 < 128; compiler schedules B-load hoisting itself.
// ---------------------------------------------------------------------------
__device__ __forceinline__ void gemm_pass(
    const ushort* __restrict__ pW,
    const ushort* Ah, const ushort* Al,
    int lane, int wid, f32x4 acc[4][2])
{
  const bf16x8* pH = (const bf16x8*)pW;
  const bf16x8* pL = (const bf16x8*)(pW + 65536);
  const int cbase = wid * 2 * 64 + lane;    // cfg = wid*2+cf
#pragma unroll
  for (int s = 0; s < 8; ++s) {
    const int slot = s * 1024 + cbase;
    bf16x8 bh0 = pH[slot];
    bf16x8 bl0 = pL[slot];
    bf16x8 bh1 = pH[slot + 64];
    bf16x8 bl1 = pL[slot + 64];
#pragma unroll
    for (int rb = 0; rb < 4; ++rb) {
      bf16x8 ah, al;
      load_afrag(Ah, Al, rb * 16 + (lane & 15), s, lane, ah, al);
      acc[rb][0] = MFMA16(al, bh0, acc[rb][0], 0, 0, 0);
      acc[rb][0] = MFMA16(ah, bl0, acc[rb][0], 0, 0, 0);
      acc[rb][0] = MFMA16(ah, bh0, acc[rb][0], 0, 0, 0);
      acc[rb][1] = MFMA16(al, bh1, acc[rb][1], 0, 0, 0);
      acc[rb][1] = MFMA16(ah, bl1, acc[rb][1], 0, 0, 0);
      acc[rb][1] = MFMA16(ah, bh1, acc[rb][1], 0, 0, 0);
    }
  }
}

// ---------------------------------------------------------------------------
// conv_in edge stage: h0 -> ea1 = h0@We0b + be0b -> atomic agg/deg.
// 512 threads, 64 edges/block, 66KB LDS -> 2 blocks/CU, no spill.
// ---------------------------------------------------------------------------
__global__ __launch_bounds__(512, 4)
void edge_conv_in(const int* __restrict__ ei, const float* __restrict__ eattr,
                  const float* __restrict__ Ps, const float* __restrict__ Pd,
                  const float* __restrict__ W6, const float* __restrict__ b0,
                  const ushort* __restrict__ pW0,
                  const float* __restrict__ be0b,
                  float* __restrict__ agg, float* __restrict__ deg)
{
  __shared__ ushort Ah[64 * 256];
  __shared__ ushort Al[64 * 256];
  __shared__ int    sSrc[64], sDst[64];
  const int tid = threadIdx.x;
  const long e0 = (long)blockIdx.x * 64;

  if (tid < 64) {
    int dv = ei[N_EDGES + e0 + tid];
    sDst[tid] = dv;
    atomicAdd(&deg[dv], 1.0f);
  } else if (tid < 128) {
    sSrc[tid - 64] = ei[e0 + tid - 64];
  }
  __syncthreads();

  build_h0(tid, Ps, Pd, eattr, e0, W6, b0, sSrc, sDst, Ah, Al);
  __syncthreads();

  const int lane = tid & 63, wid = tid >> 6;

  f32x4 acc[4][2];
#pragma unroll
  for (int rb = 0; rb < 4; ++rb)
#pragma unroll
    for (int cf = 0; cf < 2; ++cf) acc[rb][cf] = (f32x4){0.f, 0.f, 0.f, 0.f};
  gemm_pass(pW0, Ah, Al, lane, wid, acc);

#pragma unroll
  for (int rb = 0; rb < 4; ++rb) {
    const int rbase = rb * 16 + ((lane >> 4) << 2);
#pragma unroll
    for (int cf = 0; cf < 2; ++cf) {
      const int col = wid * 32 + cf * 16 + (lane & 15);
      const float bv = be0b[col];
#pragma unroll
      for (int r = 0; r < 4; ++r)
        atomicAdd(&agg[(long)sDst[rbase + r] * HD + col], acc[rb][cf][r] + bv);
    }
  }
}

// ---------------------------------------------------------------------------
// Fused conv[0] edge MLP + predictor (ea1 algebraically folded out):
//   h0  = relu(Ps[s]+Pd[d]+ea@W6+b0)
//   h1  = relu(h0@WA + P1s[s]+P1d[d]+bA)     WA = We0b@WeE, bA = be0b@WeE+be1a
//   t   = h0@WB                              WB = We0b@Wp1  (reg-resident)
//   z   = h1@Wc + t + bc                     Wc = We1b@Wp1, bc=(be1b+be0b)@Wp1+bp1
//   out = leaky_relu(z)@Wp2 + bp2
// 512 threads, 64 edges/block, 3 sequential single-B passes, 64x32 wave tiles.
// ---------------------------------------------------------------------------
__global__ __launch_bounds__(512, 4)
void edge_pred(const int* __restrict__ ei, const float* __restrict__ eattr,
               const float* __restrict__ Ps, const float* __restrict__ Pd,
               const float* __restrict__ W6, const float* __restrict__ b0,
               const float* __restrict__ P1s, const float* __restrict__ P1d,
               const ushort* __restrict__ pWA, const ushort* __restrict__ pWB,
               const ushort* __restrict__ pWc,
               const float* __restrict__ bA, const float* __restrict__ bc,
               const float* __restrict__ Wp2, const float* __restrict__ bp2,
               float* __restrict__ out)
{
  __shared__ ushort Ah[64 * 256];
  __shared__ ushort Al[64 * 256];
  __shared__ float  sOut[64];
  __shared__ int    sSrc[64], sDst[64];
  const int tid = threadIdx.x;
  const long e0 = (long)blockIdx.x * 64;

  if (tid < 64) {
    sDst[tid] = ei[N_EDGES + e0 + tid];
    sOut[tid] = bp2[0];
  } else if (tid < 128) {
    sSrc[tid - 64] = ei[e0 + tid - 64];
  }
  __syncthreads();

  build_h0(tid, Ps, Pd, eattr, e0, W6, b0, sSrc, sDst, Ah, Al);
  __syncthreads();

  const int lane = tid & 63, wid = tid >> 6;

  // ---- pass 1: acc1 = h0@WA ----
  f32x4 acc1[4][2];
#pragma unroll
  for (int rb = 0; rb < 4; ++rb)
#pragma unroll
    for (int cf = 0; cf < 2; ++cf) acc1[rb][cf] = (f32x4){0.f, 0.f, 0.f, 0.f};
  gemm_pass(pWA, Ah, Al, lane, wid, acc1);

  // ---- pass 2: accT = h0@WB ----
  f32x4 accT[4][2];
#pragma unroll
  for (int rb = 0; rb < 4; ++rb)
#pragma unroll
    for (int cf = 0; cf < 2; ++cf) accT[rb][cf] = (f32x4){0.f, 0.f, 0.f, 0.f};
  gemm_pass(pWB, Ah, Al, lane, wid, accT);
  __syncthreads();   // all h0 reads complete before overwriting the A tile

  // ---- epilogue: h1 = relu(acc1 + P1s[s]+P1d[d]+bA) -> A tile ----
#pragma unroll
  for (int rb = 0; rb < 4; ++rb) {
    const int rbase = rb * 16 + ((lane >> 4) << 2);
#pragma unroll
    for (int cf = 0; cf < 2; ++cf) {
      const int col = wid * 32 + cf * 16 + (lane & 15);
      const float bv = bA[col];
#pragma unroll
      for (int r = 0; r < 4; ++r) {
        const int row = rbase + r;
        float v = acc1[rb][cf][r] + P1s[(long)sSrc[row] * HD + col]
                                  + P1d[(long)sDst[row] * HD + col] + bv;
        write_split(Ah, Al, row, col, fmaxf(v, 0.f));
      }
    }
  }
  __syncthreads();

  // ---- pass 3: accZ = h1@Wc ----
  f32x4 accZ[4][2];
#pragma unroll
  for (int rb = 0; rb < 4; ++rb)
#pragma unroll
    for (int cf = 0; cf < 2; ++cf) accZ[rb][cf] = (f32x4){0.f, 0.f, 0.f, 0.f};
  gemm_pass(pWc, Ah, Al, lane, wid, accZ);

  // ---- finale: z = accZ + accT + bc; leaky; dot Wp2; reduce ----
  float p[4][4];
#pragma unroll
  for (int rb = 0; rb < 4; ++rb)
#pragma unroll
    for (int r = 0; r < 4; ++r) p[rb][r] = 0.f;
#pragma unroll
  for (int cf = 0; cf < 2; ++cf) {
    const int col = wid * 32 + cf * 16 + (lane & 15);
    const float w   = Wp2[col];
    const float bcv = bc[col];
#pragma unroll
    for (int rb = 0; rb < 4; ++rb)
#pragma unroll
      for (int r = 0; r < 4; ++r) {
        float z = accZ[rb][cf][r] + accT[rb][cf][r] + bcv;
        z = z > 0.f ? z : 0.01f * z;
        p[rb][r] += z * w;
      }
  }
#pragma unroll
  for (int rb = 0; rb < 4; ++rb)
#pragma unroll
    for (int r = 0; r < 4; ++r) {
      p[rb][r] += __shfl_xor(p[rb][r], 1);
      p[rb][r] += __shfl_xor(p[rb][r], 2);
      p[rb][r] += __shfl_xor(p[rb][r], 4);
      p[rb][r] += __shfl_xor(p[rb][r], 8);
    }
  if ((lane & 15) == 0) {
#pragma unroll
    for (int rb = 0; rb < 4; ++rb) {
      const int rbase = rb * 16 + ((lane >> 4) << 2);
#pragma unroll
      for (int r = 0; r < 4; ++r) atomicAdd(&sOut[rbase + r], p[rb][r]);
    }
  }
  __syncthreads();
  if (tid < 64) out[e0 + tid] = sOut[tid];
}

// ---------------------------------------------------------------------------
extern "C" void kernel_launch(void* const* d_in, const int* in_sizes, int n_in,
                              void* d_out, int out_size, void* d_ws, size_t ws_size,
                              hipStream_t stream)
{
  const float* x     = (const float*)d_in[0];
  const int*   ei    = (const int*)d_in[1];
  const float* eattr = (const float*)d_in[2];
  const float* We0a  = (const float*)d_in[3];
  const float* be0a  = (const float*)d_in[4];
  const float* We0b  = (const float*)d_in[5];
  const float* be0b  = (const float*)d_in[6];
  const float* Wn0a  = (const float*)d_in[7];
  const float* bn0a  = (const float*)d_in[8];
  const float* Wn0b  = (const float*)d_in[9];
  const float* bn0b  = (const float*)d_in[10];
  const float* We1a  = (const float*)d_in[11];
  const float* be1a  = (const float*)d_in[12];
  const float* We1b  = (const float*)d_in[13];
  const float* be1b  = (const float*)d_in[14];
  // d_in[15..18] dead (conv[0] node MLP never reaches the output)
  const float* Wp1   = (const float*)d_in[19];
  const float* bp1   = (const float*)d_in[20];
  const float* Wp2   = (const float*)d_in[21];
  const float* bp2   = (const float*)d_in[22];
  float* out = (float*)d_out;
  float* ws  = (float*)d_ws;

  float* P_s  = ws;
  float* P_d  = ws + OFF_PD;
  float* bufA = ws + OFF_BA;
  float* bufB = ws + OFF_BB;
  float* bufC = ws + OFF_BC;
  float* deg  = ws + OFF_DEG;
  float* bcB  = ws + OFF_BCV;
  float* bAB  = ws + OFF_BAV;
  ushort* pW0 = (ushort*)(ws + OFF_PW0);

  // composite-weight area inside bufB (dead after P1s/P1d are produced)
  float*  WAf = ws + OFF_BB;
  float*  WBf = ws + OFF_BB + 65536;
  float*  WcF = ws + OFF_BB + 131072;
  ushort* pWA = (ushort*)(ws + OFF_BB + 196608);
  ushort* pWB = (ushort*)(ws + OFF_BB + 262144);
  ushort* pWc = (ushort*)(ws + OFF_BB + 327680);

  const float* W6  = We0a + 1024 * HD;   // edge_attr rows of We0a
  const float* WeE = We1a + 512 * HD;    // ea1 rows of We1a

  // zero agg + deg (contiguous)
  hipMemsetAsync(bufC, 0, (2560000 + 10000) * sizeof(float), stream);

  const int ngrid = (N_NODES + 63) / 64;   // 157
  const int egrid = N_EDGES / 64;          // 5000

  // node projections (paired: P_s/P_d in one launch) + conv_in prep
  node_gemm<<<dim3(ngrid, 2), 256, 0, stream>>>(x, 512, nullptr, 0, nullptr,
      We0a, nullptr, P_s, N_NODES, 0, We0a + 512 * HD, P_d);
  prep_split<<<32, 256, 0, stream>>>(We0b, pW0, pW0 + 65536);
  bias_fold_k<<<1, 256, 0, stream>>>(be1b, be0b, Wp1, bp1, bcB);     // bc'
  bias_fold_k<<<1, 256, 0, stream>>>(be0b, nullptr, WeE, be1a, bAB); // bA

  // conv_in edge stage -> agg, deg
  edge_conv_in<<<egrid, 512, 0, stream>>>(ei, eattr, P_s, P_d, W6, be0a,
                                          pW0, be0b, bufC, deg);
  rdeg_k<<<(N_NODES + 255) / 256, 256, 0, stream>>>(deg);

  // node pipeline
  node_gemm<<<dim3(ngrid, 1), 256, 0, stream>>>(x, 512, bufC, 256, deg,
      Wn0a, bn0a, bufA, N_NODES, 1, nullptr, nullptr);                 // t1
  node_gemm<<<dim3(ngrid, 1), 256, 0, stream>>>(bufA, 256, nullptr, 0, nullptr,
      Wn0b, bn0b, bufB, N_NODES, 0, nullptr, nullptr);                 // x1
  node_gemm<<<dim3(ngrid, 2), 256, 0, stream>>>(bufB, 256, nullptr, 0, nullptr,
      We1a, nullptr, bufA, N_NODES, 0, We1a + 256 * HD, bufC);         // P1s | P1d

  // composite weights: WA=We0b@WeE, WB=We0b@Wp1 (paired), Wc=We1b@Wp1
  node_gemm<<<dim3(4, 2), 256, 0, stream>>>(We0b, 256, nullptr, 0, nullptr,
      WeE, nullptr, WAf, 256, 0, Wp1, WBf);
  node_gemm<<<dim3(4, 1), 256, 0, stream>>>(We1b, 256, nullptr, 0, nullptr,
      Wp1, nullptr, WcF, 256, 0, nullptr, nullptr);
  prep_split<<<32, 256, 0, stream>>>(WAf, pWA, pWA + 65536);
  prep_split<<<32, 256, 0, stream>>>(WBf, pWB, pWB + 65536);
  prep_split<<<32, 256, 0, stream>>>(WcF, pWc, pWc + 65536);

  // fused conv[0] edge MLP + predictor
  edge_pred<<<egrid, 512, 0, stream>>>(ei, eattr, P_s, P_d, W6, be0a,
      bufA, bufC, pWA, pWB, pWc, bAB, bcB, Wp2, bp2, out);
}